// Round 11
// baseline (629.135 us; speedup 1.0000x reference)
//
#include <hip/hip_runtime.h>
#include <cstdint>

// ---------------- problem constants ----------------
#define NB 64        // batch
#define TT 8         // timesteps
#define NN 2000      // nodes
#define NF 16        // in features
#define NCH 64       // channels
#define NPAD 2048    // padded node dim
#define BCD 4096     // NB*NCH
#define ITEMS 128000 // NB*NN

// ws offsets (floats). x2 aliases [adpF|St] (both dead before GEMM2 writes x2).
#define OFF_ADPF  0                         // fp32 adp [2048][2048] = 4194304
#define OFF_ST    4194304                   // bf16 St [4096][2048]  = 4194304 floats
#define OFF_X2    0                         // fp32 x2 [2048][4096]  = 8388608 (alias)
#define OFF_ADPT  8388608                   // bf16 adpT [2048][2048] = 2097152 floats
#define OFF_S     10485760                  // fp32 S [2048][4096]   = 8388608
#define OFF_X1F   18874368                  // fp32 x1 [2048][4096]  = 8388608
#define OFF_X1T   27262976                  // bf16 x1t [4096][2048] = 4194304 floats
#define OFF_C01   31457280                  // 128
#define OFF_WGCNT (OFF_C01 + 128)           // 12288
#define OFF_W1TT  (OFF_WGCNT + 12288)       // 8192
#define OFF_PART  (OFF_W1TT + 8192)         // 270336
#define OFF_RED   (OFF_PART + 270336)       // 136
#define OFF_WAW   (OFF_RED + 136)           // [3][2 taps][128][64] bf16 = 24576 floats
#define OFF_SWW   (OFF_WAW + 24576)         // [3][64][64] bf16 = 6144
#define OFF_WSTW  (OFF_SWW + 6144)          // [64][64] bf16 (K=64, k<16 real) = 2048

// chunk-XOR swizzle on the k dimension (8-bf16 chunks within 64-k tiles)
#define SWZK(k, x) (((k) & ~63) | (((((k) >> 3) & 7) ^ ((x) & 7)) << 3) | ((k) & 7))
// gbuf row swizzle (8 chunks/row)
#define GSWZ(n) ((((n) >> 3) ^ (n)) & 7)

typedef __attribute__((ext_vector_type(8))) short short8;
typedef __attribute__((ext_vector_type(4))) float f32x4;
typedef const __attribute__((address_space(1))) uint32_t* gas_t;
typedef __attribute__((address_space(3))) uint32_t* las_t;

__device__ __forceinline__ float fast_rcp(float x) { return __builtin_amdgcn_rcpf(x); }
__device__ __forceinline__ float fast_tanh(float x) {
    x = fminf(fmaxf(x, -10.f), 10.f);
    float e = __expf(2.f * x);
    return (e - 1.f) * fast_rcp(e + 1.f);
}
__device__ __forceinline__ float fast_sigmoid(float x) {
    return fast_rcp(1.f + __expf(-x));
}
// RNE f32->bf16 (proven bit-path; v_cvt_pk_bf16_f32 regressed absmax 13x in r8)
__device__ __forceinline__ unsigned short f2bf(float f) {
    uint32_t u = __float_as_uint(f);
    u += 0x7fff + ((u >> 16) & 1);
    return (unsigned short)(u >> 16);
}
__device__ __forceinline__ float bf2f(unsigned short b) {
    return __uint_as_float(((uint32_t)b) << 16);
}

// ---------------- K0: precompute (parallelized over 64 blocks) ----------------
__global__ __launch_bounds__(256) void prep_kernel(const float* __restrict__ gcn_w,
                            const float* __restrict__ h0_w1, const float* __restrict__ h0_b1,
                            const float* __restrict__ h1_w1, const float* __restrict__ h1_b1,
                            const float* __restrict__ task_emb,
                            const float* __restrict__ filt_w, const float* __restrict__ gate_w,
                            const float* __restrict__ skip_w, const float* __restrict__ start_w,
                            float* __restrict__ c01, float* __restrict__ wgcnT,
                            float* __restrict__ w1tT,
                            unsigned short* __restrict__ waw,
                            unsigned short* __restrict__ sww,
                            unsigned short* __restrict__ wstw)
{
    const int GS = 64 * 256;
    int gt = blockIdx.x * 256 + threadIdx.x;
    for (int idx = gt; idx < 64 * 192; idx += GS) {
        int o = idx / 192, j = idx % 192;
        wgcnT[j * 64 + o] = gcn_w[idx];
    }
    for (int idx = gt; idx < 4096; idx += GS) {
        int o = idx >> 6, c = idx & 63;
        w1tT[c * 64 + o]        = h0_w1[o * 128 + 64 + c];
        w1tT[4096 + c * 64 + o] = h1_w1[o * 128 + 64 + c];
    }
    // WA[L][p][r][k=c]: r<64 filt row r, r>=64 gate row r-64; tap p; chunk-swizzled ^(r&7)
    for (int job = gt; job < 3 * 2 * 128 * 8; job += GS) {
        int L = job / 2048, rem = job % 2048;
        int p = rem >> 10, rem2 = rem & 1023;
        int r = rem2 >> 3, chp = rem2 & 7;
        int cho = chp ^ (r & 7);
        #pragma unroll
        for (int i = 0; i < 8; ++i) {
            int c = cho * 8 + i;
            float v = (r < 64) ? filt_w[L * 8192 + r * 128 + c * 2 + p]
                               : gate_w[L * 8192 + (r - 64) * 128 + c * 2 + p];
            waw[((L * 2 + p) * 128 + r) * 64 + chp * 8 + i] = f2bf(v);
        }
    }
    for (int job = gt; job < 3 * 64 * 8; job += GS) {
        int L = job / 512, rem = job % 512;
        int r = rem >> 3, chp = rem & 7;
        int cho = chp ^ (r & 7);
        #pragma unroll
        for (int i = 0; i < 8; ++i)
            sww[(L * 64 + r) * 64 + chp * 8 + i] = f2bf(skip_w[L * 4096 + r * 64 + cho * 8 + i]);
    }
    // start W: [64 r][64 k] (k<16 real), chunk-swizzled ^(r&7)
    for (int job = gt; job < 64 * 8; job += GS) {
        int r = job >> 3, chp = job & 7;
        int cho = chp ^ (r & 7);
        #pragma unroll
        for (int i = 0; i < 8; ++i) {
            int k = cho * 8 + i;
            wstw[r * 64 + chp * 8 + i] = (k < 16) ? f2bf(start_w[r * 16 + k]) : (unsigned short)0;
        }
    }
    if (gt < 128) {
        int head = gt >> 6, o = gt & 63;
        const float* w1 = head ? h1_w1 : h0_w1;
        const float* b1 = head ? h1_b1 : h0_b1;
        float a = b1[o];
        for (int k = 0; k < 64; ++k) a = fmaf(w1[o * 128 + k], task_emb[k], a);
        c01[gt] = a;
    }
}

// ---------------- K1: adpF = softmax(relu(nv1@nv2), axis=1), fp32, coalesced ----------------
__global__ __launch_bounds__(256) void adp_kernel(const float* __restrict__ nv1,
                                                  const float* __restrict__ nv2,
                                                  float* __restrict__ adpF)
{
    __shared__ float nv1s[10];
    __shared__ float rbuf[4];
    int tid = threadIdx.x;
    int r = blockIdx.x;
    if (tid < 10) nv1s[tid] = nv1[r * 10 + tid];
    __syncthreads();

    float val[8];
    float vmax = -3.4e38f;
    #pragma unroll
    for (int s = 0; s < 8; ++s) {
        int j = tid + s * 256;
        if (j < NN) {
            float v = 0.f;
            #pragma unroll
            for (int k = 0; k < 10; ++k) v = fmaf(nv1s[k], nv2[k * NN + j], v);
            v = fmaxf(v, 0.f);
            val[s] = v;
            vmax = fmaxf(vmax, v);
        } else val[s] = -3.4e38f;
    }
    for (int off = 32; off; off >>= 1) vmax = fmaxf(vmax, __shfl_down(vmax, off, 64));
    if ((tid & 63) == 0) rbuf[tid >> 6] = vmax;
    __syncthreads();
    vmax = fmaxf(fmaxf(rbuf[0], rbuf[1]), fmaxf(rbuf[2], rbuf[3]));
    __syncthreads();
    float sum = 0.f;
    #pragma unroll
    for (int s = 0; s < 8; ++s) {
        int j = tid + s * 256;
        if (j < NN) { val[s] = expf(val[s] - vmax); sum += val[s]; }
    }
    for (int off = 32; off; off >>= 1) sum += __shfl_down(sum, off, 64);
    if ((tid & 63) == 0) rbuf[tid >> 6] = sum;
    __syncthreads();
    sum = rbuf[0] + rbuf[1] + rbuf[2] + rbuf[3];
    float inv = 1.f / sum;
    #pragma unroll
    for (int s = 0; s < 8; ++s) {
        int j = tid + s * 256;
        if (j < NN) adpF[(size_t)r * NPAD + j] = val[s] * inv;
    }
}

// ---------------- K1b: adpT = transpose(adpF) -> bf16, k-swizzled, zero-padded ----------------
__global__ __launch_bounds__(256) void transpose_adp(const float* __restrict__ adpF,
                                                     unsigned short* __restrict__ adpT)
{
    __shared__ float tile[64][65];
    int tid = threadIdx.x;
    int r0 = blockIdx.x * 64;
    int j0 = blockIdx.y * 64;
    #pragma unroll
    for (int s = 0; s < 16; ++s) {
        int idx = s * 256 + tid;
        int i = idx >> 6, jj = idx & 63;
        int r = r0 + i, j = j0 + jj;
        tile[i][jj] = (r < NN && j < NN) ? adpF[(size_t)r * NPAD + j] : 0.f;
    }
    __syncthreads();
    #pragma unroll
    for (int s = 0; s < 2; ++s) {
        int slot = s * 256 + tid;
        int j = slot >> 3, ch = slot & 7;
        short8 v;
        #pragma unroll
        for (int e = 0; e < 8; ++e) v[e] = (short)f2bf(tile[ch * 8 + e][j]);
        *(short8*)&adpT[(size_t)(j0 + j) * NPAD + r0 + ((ch ^ (j & 7)) << 3)] = v;
    }
}

// ---------------- K2: fused temporal stack (MFMA, 16 items/block, 2 blocks/CU) ----------------
// LDS (73.5 KB): xb[128 rows n=g*8+t][64 k=c] (16KB), gbuf[128][64] (16KB),
//   WA[2 taps][128][64] per-layer (32KB), SW[64][64] per-layer (8KB), bias (1.5KB).
// Conv as two K=64 MFMA chains (tap0 on row n, tap1 on row n+D) in the exact old
// kstep order -> bit-identical to the K=128 duplicated-tap version.
template<int NG, int WOUT, int D>
__device__ __forceinline__ void mfma_phaseB(int L,
    const unsigned short* __restrict__ xb, unsigned short* __restrict__ gbuf,
    const unsigned short* __restrict__ WA, const float* __restrict__ biasAll,
    int wave, int lr, int lk)
{
    if (wave >= NG) return;
    int idx = wave * 16 + lr;
    int n = (idx / WOUT) * 8 + (idx % WOUT);
    f32x4 aF[4], aG[4];
    #pragma unroll
    for (int mt = 0; mt < 4; ++mt) {
        aF[mt] = (f32x4){0.f, 0.f, 0.f, 0.f};
        aG[mt] = (f32x4){0.f, 0.f, 0.f, 0.f};
    }
    #pragma unroll
    for (int p = 0; p < 2; ++p) {
        int nb = n + p * D;
        const unsigned short* WAp = WA + p * 8192;
        #pragma unroll
        for (int ks = 0; ks < 2; ++ks) {
            short8 bv = *(const short8*)&xb[(nb * 8 + ((ks * 4 + lk) ^ (nb & 7))) * 8];
            #pragma unroll
            for (int mt = 0; mt < 4; ++mt) {
                int r = mt * 16 + lr;
                short8 av = *(const short8*)&WAp[(r * 8 + ((ks * 4 + lk) ^ (r & 7))) * 8];
                aF[mt] = __builtin_amdgcn_mfma_f32_16x16x32_bf16(av, bv, aF[mt], 0, 0, 0);
            }
            #pragma unroll
            for (int mt = 0; mt < 4; ++mt) {
                int r = (mt + 4) * 16 + lr;
                short8 av = *(const short8*)&WAp[(r * 8 + ((ks * 4 + lk) ^ (r & 7))) * 8];
                aG[mt] = __builtin_amdgcn_mfma_f32_16x16x32_bf16(av, bv, aG[mt], 0, 0, 0);
            }
        }
    }
    int gs = GSWZ(n);
    #pragma unroll
    for (int mt = 0; mt < 4; ++mt) {
        int ob = mt * 16 + lk * 4;
        ushort4 p;
        p.x = f2bf(fast_tanh(aF[mt][0] + biasAll[L * 128 + ob + 0]) * fast_sigmoid(aG[mt][0] + biasAll[L * 128 + 64 + ob + 0]));
        p.y = f2bf(fast_tanh(aF[mt][1] + biasAll[L * 128 + ob + 1]) * fast_sigmoid(aG[mt][1] + biasAll[L * 128 + 64 + ob + 1]));
        p.z = f2bf(fast_tanh(aF[mt][2] + biasAll[L * 128 + ob + 2]) * fast_sigmoid(aG[mt][2] + biasAll[L * 128 + 64 + ob + 2]));
        p.w = f2bf(fast_tanh(aF[mt][3] + biasAll[L * 128 + ob + 3]) * fast_sigmoid(aG[mt][3] + biasAll[L * 128 + 64 + ob + 3]));
        *(ushort4*)&gbuf[((n * 8) + ((mt * 2 + (lk >> 1)) ^ gs)) * 8 + (lk & 1) * 4] = p;
    }
}

// wave = item g; writes each x value ONCE (single xb array serves both taps).
template<int L, int D, int WOUT>
__device__ __forceinline__ void phaseC_conv(unsigned short* __restrict__ xb,
    const unsigned short* __restrict__ gbuf,
    const float* __restrict__ bn_g, const float* __restrict__ bn_b,
    float xreg[8], int wave, int o)
{
    float bsc = bn_g[L * 64 + o] * rsqrtf(1.0f + 1e-5f);
    float bsh = bn_b[L * 64 + o];
    int g = wave;
    #pragma unroll
    for (int t = 0; t < WOUT; ++t) {
        int n = g * 8 + t;
        float gv = bf2f(gbuf[(n * 8 + ((o >> 3) ^ GSWZ(n))) * 8 + (o & 7)]);
        float nx = (gv + xreg[t + D]) * bsc + bsh;
        xreg[t] = nx;
        xb[(n * 8 + ((o >> 3) ^ (n & 7))) * 8 + (o & 7)] = f2bf(nx);
    }
}

__device__ __forceinline__ void phaseC_skip(int LASTT,
    const unsigned short* __restrict__ gbuf, const unsigned short* __restrict__ SW,
    f32x4 skacc[4], int wave, int lr, int lk)
{
    if (wave != 0) return;
    int n = lr * 8 + LASTT;
    int gs = GSWZ(n);
    #pragma unroll
    for (int ks = 0; ks < 2; ++ks) {
        short8 bv = *(const short8*)&gbuf[(n * 8 + ((ks * 4 + lk) ^ gs)) * 8];
        #pragma unroll
        for (int mt = 0; mt < 4; ++mt) {
            int r = mt * 16 + lr;
            short8 av = *(const short8*)&SW[(r * 8 + ((ks * 4 + lk) ^ (r & 7))) * 8];
            skacc[mt] = __builtin_amdgcn_mfma_f32_16x16x32_bf16(av, bv, skacc[mt], 0, 0, 0);
        }
    }
}

__global__ __launch_bounds__(1024) void temporal_kernel(
    const float* __restrict__ X,
    const float* __restrict__ start_b,
    const unsigned short* __restrict__ waw,
    const unsigned short* __restrict__ sww,
    const unsigned short* __restrict__ wstw,
    const float* __restrict__ filt_b, const float* __restrict__ gate_b,
    const float* __restrict__ skip_b,
    const float* __restrict__ bn_g, const float* __restrict__ bn_b,
    float* __restrict__ S, unsigned short* __restrict__ St)
{
    extern __shared__ float smem[];
    unsigned short* xb   = (unsigned short*)smem;              // 8192 ush
    unsigned short* gbuf = (unsigned short*)(smem + 4096);     // 8192 ush
    unsigned short* WA   = (unsigned short*)(smem + 8192);     // 16384 ush (2 taps x 128 x 64)
    unsigned short* SW   = (unsigned short*)(smem + 16384);    // 4096 ush
    float* biasAll       = smem + 18432;                       // 384 f32

    int tid = threadIdx.x;
    int wave = tid >> 6, lane = tid & 63;
    int lr = lane & 15, lk = lane >> 4;
    int o = lane;
    int item0 = blockIdx.x * 16;

    // ---- init: stage start-W into WA rows 0..63, bias, X -> xb ----
    if (tid < 512)
        __builtin_amdgcn_global_load_lds((gas_t)(wstw + tid * 8), (las_t)(WA + tid * 8), 16, 0, 0);
    if (tid < 384) {
        int L = tid >> 7, oo = tid & 127;
        biasAll[tid] = (oo < 64) ? filt_b[L * 64 + oo] : gate_b[L * 64 + oo - 64];
    }
    {   // X -> xb: n = tid>>3 (0..127), physical chunk c = tid&7
        int n = tid >> 3, c = tid & 7;
        int g = n >> 3, t = n & 7;
        int ig = item0 + g, b = ig / NN, nn = ig - b * NN;
        int cho = c ^ (n & 7);
        short8 v = {0, 0, 0, 0, 0, 0, 0, 0};
        if (cho < 2) {
            const float* src = &X[((size_t)(b * TT + t) * NN + nn) * NF + cho * 8];
            float4 f0 = *(const float4*)src;
            float4 f1 = *(const float4*)(src + 4);
            v[0] = (short)f2bf(f0.x); v[1] = (short)f2bf(f0.y);
            v[2] = (short)f2bf(f0.z); v[3] = (short)f2bf(f0.w);
            v[4] = (short)f2bf(f1.x); v[5] = (short)f2bf(f1.y);
            v[6] = (short)f2bf(f1.z); v[7] = (short)f2bf(f1.w);
        }
        *(short8*)&xb[(n * 8 + c) * 8] = v;
    }
    __syncthreads();

    // ---- start conv MFMA (K=32: ks=0 only; rows 0..127 via waves 0..7) + stage SW L0 ----
    if (wave < 8) {
        f32x4 aS[4];
        #pragma unroll
        for (int mt = 0; mt < 4; ++mt) aS[mt] = (f32x4){0.f, 0.f, 0.f, 0.f};
        int n = wave * 16 + lr;
        short8 bv = *(const short8*)&xb[(n * 8 + (lk ^ (n & 7))) * 8];
        #pragma unroll
        for (int mt = 0; mt < 4; ++mt) {
            int r = mt * 16 + lr;
            short8 av = *(const short8*)&WA[(r * 8 + (lk ^ (r & 7))) * 8];
            aS[mt] = __builtin_amdgcn_mfma_f32_16x16x32_bf16(av, bv, aS[mt], 0, 0, 0);
        }
        int gs = GSWZ(n);
        #pragma unroll
        for (int mt = 0; mt < 4; ++mt) {
            ushort4 p;
            p.x = f2bf(aS[mt][0]); p.y = f2bf(aS[mt][1]);
            p.z = f2bf(aS[mt][2]); p.w = f2bf(aS[mt][3]);
            *(ushort4*)&gbuf[((n * 8) + ((mt * 2 + (lk >> 1)) ^ gs)) * 8 + (lk & 1) * 4] = p;
        }
    }
    if (tid < 512)
        __builtin_amdgcn_global_load_lds((gas_t)(sww + tid * 8), (las_t)(SW + tid * 8), 16, 0, 0);
    __syncthreads();

    float xreg[8];
    f32x4 skacc[4];
    #pragma unroll
    for (int mt = 0; mt < 4; ++mt) skacc[mt] = (f32x4){0.f, 0.f, 0.f, 0.f};

    // ---- C0: x = start_out + start_b (wave = item); write all 8 t rows; stage WA L0 ----
    {
        __builtin_amdgcn_global_load_lds((gas_t)(waw + (size_t)tid * 8),
                                         (las_t)(WA + tid * 8), 16, 0, 0);
        __builtin_amdgcn_global_load_lds((gas_t)(waw + (size_t)(tid + 1024) * 8),
                                         (las_t)(WA + (tid + 1024) * 8), 16, 0, 0);
        float sb = start_b[o];
        int g = wave;
        #pragma unroll
        for (int t = 0; t < 8; ++t) {
            int n = g * 8 + t;
            float gv = bf2f(gbuf[(n * 8 + ((o >> 3) ^ GSWZ(n))) * 8 + (o & 7)]) + sb;
            xreg[t] = gv;
            xb[(n * 8 + ((o >> 3) ^ (n & 7))) * 8 + (o & 7)] = f2bf(gv);
        }
    }
    __syncthreads();

    // ---- B0 (live t<7: 112 rows = 7 groups) ----
    mfma_phaseB<7, 7, 1>(0, xb, gbuf, WA, biasAll, wave, lr, lk);
    __syncthreads();
    // ---- PC0: skip(0) + conv(0) + stage WA L1 ----
    phaseC_skip(6, gbuf, SW, skacc, wave, lr, lk);
    phaseC_conv<0, 1, 7>(xb, gbuf, bn_g, bn_b, xreg, wave, o);
    __builtin_amdgcn_global_load_lds((gas_t)(waw + (size_t)(16384 + tid * 8)),
                                     (las_t)(WA + tid * 8), 16, 0, 0);
    __builtin_amdgcn_global_load_lds((gas_t)(waw + (size_t)(16384 + (tid + 1024) * 8)),
                                     (las_t)(WA + (tid + 1024) * 8), 16, 0, 0);
    __syncthreads();

    // ---- B1 (live t<5: 80 rows = 5 groups) + stage SW L1 ----
    mfma_phaseB<5, 5, 2>(1, xb, gbuf, WA, biasAll, wave, lr, lk);
    if (tid < 512)
        __builtin_amdgcn_global_load_lds((gas_t)(sww + (size_t)(4096 + tid * 8)),
                                         (las_t)(SW + tid * 8), 16, 0, 0);
    __syncthreads();
    // ---- PC1: skip(1) + conv(1) + stage WA L2 ----
    phaseC_skip(4, gbuf, SW, skacc, wave, lr, lk);
    phaseC_conv<1, 2, 5>(xb, gbuf, bn_g, bn_b, xreg, wave, o);
    __builtin_amdgcn_global_load_lds((gas_t)(waw + (size_t)(32768 + tid * 8)),
                                     (las_t)(WA + tid * 8), 16, 0, 0);
    __builtin_amdgcn_global_load_lds((gas_t)(waw + (size_t)(32768 + (tid + 1024) * 8)),
                                     (las_t)(WA + (tid + 1024) * 8), 16, 0, 0);
    __syncthreads();

    // ---- B2 (live t<1: 16 rows = 1 group) + stage SW L2 ----
    mfma_phaseB<1, 1, 4>(2, xb, gbuf, WA, biasAll, wave, lr, lk);
    if (tid < 512)
        __builtin_amdgcn_global_load_lds((gas_t)(sww + (size_t)(8192 + tid * 8)),
                                         (las_t)(SW + tid * 8), 16, 0, 0);
    __syncthreads();
    // ---- PC2: skip(2) ----
    phaseC_skip(0, gbuf, SW, skacc, wave, lr, lk);

    // ---- final skip writes (wave 0 holds skip[o][g] for 16 items) ----
    if (wave == 0) {
        int ig = item0 + lr, b = ig / NN, nn = ig - b * NN;
        #pragma unroll
        for (int mt = 0; mt < 4; ++mt) {
            #pragma unroll
            for (int j = 0; j < 4; ++j) {
                int oo = mt * 16 + lk * 4 + j;
                float v = skacc[mt][j] + skip_b[oo] + skip_b[64 + oo] + skip_b[128 + oo];
                int bc = b * 64 + oo;
                S[(size_t)nn * BCD + bc] = v;
                St[(size_t)bc * NPAD + SWZK(nn, oo)] = f2bf(v);
            }
        }
    }
}

// ---------------- K3: bf16 MFMA GEMM, C[m][n] = sum_k A[m][k]*B[n][k] ----------------
__global__ __launch_bounds__(256) void gemm_mfma(
    const unsigned short* __restrict__ A, const unsigned short* __restrict__ B,
    float* __restrict__ Cf, unsigned short* __restrict__ Ct)
{
    __shared__ unsigned short As[128 * 64];
    __shared__ unsigned short Bs[128 * 64];
    int tid = threadIdx.x;
    int wave = tid >> 6, lane = tid & 63;
    int lk = lane >> 4, lr = lane & 15;
    int n0 = blockIdx.x * 128, m0 = blockIdx.y * 128;
    int wm = wave >> 1, wn = wave & 1;

    f32x4 acc[4][4];
    #pragma unroll
    for (int i = 0; i < 4; ++i)
        #pragma unroll
        for (int j = 0; j < 4; ++j)
            acc[i][j] = (f32x4){0.f, 0.f, 0.f, 0.f};

    for (int k0 = 0; k0 < NPAD; k0 += 64) {
        #pragma unroll
        for (int i = 0; i < 4; ++i) {
            int chunk = wave * 4 + i;
            int row = chunk * 8 + (lane >> 3);
            int koff = (lane & 7) * 8;
            __builtin_amdgcn_global_load_lds(
                (gas_t)(A + (size_t)(m0 + row) * NPAD + k0 + koff),
                (las_t)(&As[chunk * 512]), 16, 0, 0);
            __builtin_amdgcn_global_load_lds(
                (gas_t)(B + (size_t)(n0 + row) * NPAD + k0 + koff),
                (las_t)(&Bs[chunk * 512]), 16, 0, 0);
        }
        __syncthreads();
        #pragma unroll
        for (int s = 0; s < 2; ++s) {
            short8 av[4], bv[4];
            #pragma unroll
            for (int f = 0; f < 4; ++f) {
                int m = wm * 64 + f * 16 + lr;
                int ca = ((s * 4 + lk) ^ (m & 7));
                av[f] = *(const short8*)&As[m * 64 + ca * 8];
                int n = wn * 64 + f * 16 + lr;
                int cb = ((s * 4 + lk) ^ (n & 7));
                bv[f] = *(const short8*)&Bs[n * 64 + cb * 8];
            }
            #pragma unroll
            for (int fi = 0; fi < 4; ++fi)
                #pragma unroll
                for (int fj = 0; fj < 4; ++fj)
                    acc[fi][fj] = __builtin_amdgcn_mfma_f32_16x16x32_bf16(
                        av[fi], bv[fj], acc[fi][fj], 0, 0, 0);
        }
        __syncthreads();
    }

    #pragma unroll
    for (int fi = 0; fi < 4; ++fi) {
        #pragma unroll
        for (int fj = 0; fj < 4; ++fj) {
            int m = m0 + wm * 64 + fi * 16 + lk * 4;
            int n = n0 + wn * 64 + fj * 16 + lr;
            f32x4 v = acc[fi][fj];
            if (Cf) {
                Cf[(size_t)(m + 0) * BCD + n] = v[0];
                Cf[(size_t)(m + 1) * BCD + n] = v[1];
                Cf[(size_t)(m + 2) * BCD + n] = v[2];
                Cf[(size_t)(m + 3) * BCD + n] = v[3];
            }
            if (Ct) {
                ushort4 p;
                p.x = f2bf(v[0]); p.y = f2bf(v[1]);
                p.z = f2bf(v[2]); p.w = f2bf(v[3]);
                *(ushort4*)&Ct[(size_t)n * NPAD + SWZK(m, n)] = p;
            }
        }
    }
}

// ---------------- K4: gcn 1x1 + heads + outputs + partial reductions ----------------
__global__ __launch_bounds__(256) void head_kernel(
    const float* __restrict__ S, const float* __restrict__ x1f,
    const float* __restrict__ x2,
    const float* __restrict__ wgcnT, const float* __restrict__ gcn_b,
    const float* __restrict__ c01, const float* __restrict__ w1tT,
    const float* __restrict__ h0_w2, const float* __restrict__ h0_b2,
    const float* __restrict__ h1_w2, const float* __restrict__ h1_b2,
    const int* __restrict__ Ct, const float* __restrict__ Yf,
    float* __restrict__ out, float* __restrict__ partials)
{
    __shared__ float hl[4][4][192];
    __shared__ float gxl[4][4][64];
    int tid = threadIdx.x;
    int wave = tid >> 6, o = tid & 63;
    int wid = blockIdx.x * 4 + wave;
    float w2a = h0_w2[o], w2b = h1_w2[o];
    float b20 = h0_b2[0], b21 = h1_b2[0];
    float cb = gcn_b[o], c0a = c01[o], c0b = c01[64 + o];

    float accT = 0.f, accC = 0.f, bce = 0.f, cT = 0.f, cC = 0.f;

    for (int base = wid * 4; base < ITEMS; base += 2048 * 4) {
        #pragma unroll
        for (int it = 0; it < 4; ++it) {
            int item = base + it;
            int b = item / NN, n = item - b * NN;
            int bc = b * 64 + o;
            hl[wave][it][o]       = S[(size_t)n * BCD + bc];
            hl[wave][it][64 + o]  = x1f[(size_t)n * BCD + bc];
            hl[wave][it][128 + o] = x2[(size_t)n * BCD + bc];
        }
        float a0 = cb, a1 = cb, a2 = cb, a3 = cb;
        for (int j = 0; j < 192; ++j) {
            float w = wgcnT[j * 64 + o];
            a0 = fmaf(w, hl[wave][0][j], a0);
            a1 = fmaf(w, hl[wave][1][j], a1);
            a2 = fmaf(w, hl[wave][2][j], a2);
            a3 = fmaf(w, hl[wave][3][j], a3);
        }
        float gxv[4] = {fmaxf(a0, 0.f), fmaxf(a1, 0.f), fmaxf(a2, 0.f), fmaxf(a3, 0.f)};
        #pragma unroll
        for (int it = 0; it < 4; ++it) gxl[wave][it][o] = gxv[it];

        float p0[4], p1[4];
        #pragma unroll
        for (int it = 0; it < 4; ++it) { p0[it] = c0a; p1[it] = c0b; }
        for (int c = 0; c < 64; ++c) {
            float w0 = w1tT[c * 64 + o];
            float w1 = w1tT[4096 + c * 64 + o];
            float g0 = gxl[wave][0][c], g1 = gxl[wave][1][c];
            float g2 = gxl[wave][2][c], g3 = gxl[wave][3][c];
            p0[0] = fmaf(w0, g0, p0[0]); p0[1] = fmaf(w0, g1, p0[1]);
            p0[2] = fmaf(w0, g2, p0[2]); p0[3] = fmaf(w0, g3, p0[3]);
            p1[0] = fmaf(w1, g0, p1[0]); p1[1] = fmaf(w1, g1, p1[1]);
            p1[2] = fmaf(w1, g2, p1[2]); p1[3] = fmaf(w1, g3, p1[3]);
        }
        #pragma unroll
        for (int it = 0; it < 4; ++it) {
            float r0 = w2a * fmaxf(p0[it], 0.f);
            float r1 = w2b * fmaxf(p1[it], 0.f);
            #pragma unroll
            for (int off = 32; off; off >>= 1) {
                r0 += __shfl_down(r0, off, 64);
                r1 += __shfl_down(r1, off, 64);
            }
            int item = base + it;
            int tt = Ct[item];
            if (o == 0) {
                float y0 = 1.f / (1.f + expf(-(r0 + b20)));
                float y1 = 1.f / (1.f + expf(-(r1 + b21)));
                float y = (tt > 0) ? y1 : y0;
                out[1 + item] = y;
                out[1 + ITEMS + item] = y0;
                out[1 + 2 * ITEMS + item] = y1;
                float yc = fminf(fmaxf(y, 1e-7f), 1.f - 1e-7f);
                float Yv = Yf[item];
                bce -= Yv * logf(yc) + (1.f - Yv) * logf(1.f - yc);
                if (tt > 0) cT += 1.f; else cC += 1.f;
            }
            if (tt > 0) accT += gxv[it]; else accC += gxv[it];
        }
    }
    partials[wid * 132 + o] = accT;
    partials[wid * 132 + 64 + o] = accC;
    if (o == 0) {
        partials[wid * 132 + 128] = bce;
        partials[wid * 132 + 129] = cT;
        partials[wid * 132 + 130] = cC;
    }
}

// ---------------- K5a: parallel slot reduce ----------------
__global__ __launch_bounds__(256) void reduce_kernel(const float* __restrict__ partials,
                                                     float* __restrict__ red)
{
    __shared__ float rb[4];
    int slot = blockIdx.x;
    int tid = threadIdx.x;
    float s = 0.f;
    for (int w = tid; w < 2048; w += 256) s += partials[w * 132 + slot];
    #pragma unroll
    for (int off = 32; off; off >>= 1) s += __shfl_down(s, off, 64);
    if ((tid & 63) == 0) rb[tid >> 6] = s;
    __syncthreads();
    if (tid == 0) red[slot] = rb[0] + rb[1] + rb[2] + rb[3];
}

// ---------------- K5b: final loss ----------------
__global__ void final_kernel(const float* __restrict__ red,
                             const float* __restrict__ task_emb,
                             float* __restrict__ out)
{
    int tid = threadIdx.x; // 64
    float cT = red[129], cC = red[130];
    float iT = 1.f / fmaxf(cT, 1.f), iC = 1.f / fmaxf(cC, 1.f);
    float d1 = task_emb[tid] * (cT * iT) - task_emb[tid] * (cC * iC);
    float d2 = red[tid] * iT - red[64 + tid] * iC;
    float p = d1 * d1 + d2 * d2;
    #pragma unroll
    for (int off = 32; off; off >>= 1) p += __shfl_down(p, off, 64);
    if (tid == 0) out[0] = red[128] * (1.f / (float)ITEMS) + p;
}

// ---------------- launch ----------------
extern "C" void kernel_launch(void* const* d_in, const int* in_sizes, int n_in,
                              void* d_out, int out_size, void* d_ws, size_t ws_size,
                              hipStream_t stream)
{
    const float* X       = (const float*)d_in[0];
    const int*   Ct      = (const int*)d_in[2];
    const float* Yf      = (const float*)d_in[3];
    const float* start_w = (const float*)d_in[5];
    const float* start_b = (const float*)d_in[6];
    const float* filt_w  = (const float*)d_in[7];
    const float* filt_b  = (const float*)d_in[8];
    const float* gate_w  = (const float*)d_in[9];
    const float* gate_b  = (const float*)d_in[10];
    const float* skip_w  = (const float*)d_in[11];
    const float* skip_b  = (const float*)d_in[12];
    const float* bn_g    = (const float*)d_in[13];
    const float* bn_b    = (const float*)d_in[14];
    const float* nv1     = (const float*)d_in[15];
    const float* nv2     = (const float*)d_in[16];
    const float* task    = (const float*)d_in[17];
    const float* gcn_w   = (const float*)d_in[18];
    const float* gcn_b   = (const float*)d_in[19];
    const float* h0_w1   = (const float*)d_in[20];
    const float* h0_b1   = (const float*)d_in[21];
    const float* h0_w2   = (const float*)d_in[22];
    const float* h0_b2   = (const float*)d_in[23];
    const float* h1_w1   = (const float*)d_in[24];
    const float* h1_b1   = (const float*)d_in[25];
    const float* h1_w2   = (const float*)d_in[26];
    const float* h1_b2   = (const float*)d_in[27];

    float* ws    = (float*)d_ws;
    float* adpF  = ws + OFF_ADPF;
    unsigned short* St   = (unsigned short*)(ws + OFF_ST);
    float* x2    = ws + OFF_X2;        // aliases [adpF|St], safe by schedule
    unsigned short* adpT = (unsigned short*)(ws + OFF_ADPT);
    float* S     = ws + OFF_S;
    float* x1f   = ws + OFF_X1F;
    unsigned short* x1t  = (unsigned short*)(ws + OFF_X1T);
    float* c01   = ws + OFF_C01;
    float* wgcnT = ws + OFF_WGCNT;
    float* w1tT  = ws + OFF_W1TT;
    float* part  = ws + OFF_PART;
    float* red   = ws + OFF_RED;
    unsigned short* waw  = (unsigned short*)(ws + OFF_WAW);
    unsigned short* sww  = (unsigned short*)(ws + OFF_SWW);
    unsigned short* wstw = (unsigned short*)(ws + OFF_WSTW);
    float* outp  = (float*)d_out;

    // zero St (pad rows n in [2000,2048) must contribute 0 to GEMM1)
    hipMemsetAsync(St, 0, (size_t)BCD * NPAD * sizeof(unsigned short), stream);

    prep_kernel<<<64, 256, 0, stream>>>(gcn_w, h0_w1, h0_b1, h1_w1, h1_b1, task,
                                        filt_w, gate_w, skip_w, start_w,
                                        c01, wgcnT, w1tT, waw, sww, wstw);
    adp_kernel<<<NN, 256, 0, stream>>>(nv1, nv2, adpF);
    dim3 tg(NPAD / 64, NPAD / 64);
    transpose_adp<<<tg, 256, 0, stream>>>(adpF, adpT);

    const int K2_LDS = 18816 * 4; // 73.5 KiB dynamic LDS -> 2 blocks/CU
    hipFuncSetAttribute(reinterpret_cast<const void*>(temporal_kernel),
                        hipFuncAttributeMaxDynamicSharedMemorySize, K2_LDS);
    temporal_kernel<<<ITEMS / 16, 1024, K2_LDS, stream>>>(
        X, start_b, waw, sww, wstw, filt_b, gate_b,
        skip_b, bn_g, bn_b, S, St);

    dim3 gg(BCD / 128, NPAD / 128);
    gemm_mfma<<<gg, 256, 0, stream>>>(adpT, St, x1f, x1t);      // x1 (both layouts)
    gemm_mfma<<<gg, 256, 0, stream>>>(adpT, x1t, x2, nullptr);  // x2 = adp^T·x1

    head_kernel<<<512, 256, 0, stream>>>(S, x1f, x2, wgcnT, gcn_b, c01, w1tT,
                                         h0_w2, h0_b2, h1_w2, h1_b2,
                                         Ct, Yf, outp, part);
    reduce_kernel<<<131, 256, 0, stream>>>(part, red);
    final_kernel<<<1, 64, 0, stream>>>(red, task, outp);
}

// Round 12
// 543.968 us; speedup vs baseline: 1.1566x; 1.1566x over previous
//
#include <hip/hip_runtime.h>
#include <cstdint>

// ---------------- problem constants ----------------
#define NB 64        // batch
#define TT 8         // timesteps
#define NN 2000      // nodes
#define NF 16        // in features
#define NCH 64       // channels
#define NPAD 2048    // padded node dim
#define BCD 4096     // NB*NCH
#define ITEMS 128000 // NB*NN

// ws offsets (floats). x2 aliases [adpF|St] (both dead before GEMM2 writes x2).
#define OFF_ADPF  0                         // fp32 adp [2048][2048] = 4194304
#define OFF_ST    4194304                   // bf16 St [4096][2048]  = 4194304 floats
#define OFF_X2    0                         // fp32 x2 [2048][4096]  = 8388608 (alias)
#define OFF_ADPT  8388608                   // bf16 adpT [2048][2048] = 2097152 floats
#define OFF_S     10485760                  // fp32 S [2048][4096]   = 8388608
#define OFF_X1F   18874368                  // fp32 x1 [2048][4096]  = 8388608
#define OFF_X1T   27262976                  // bf16 x1t [4096][2048] = 4194304 floats
#define OFF_C01   31457280                  // 128
#define OFF_WGCNT (OFF_C01 + 128)           // 12288
#define OFF_W1TT  (OFF_WGCNT + 12288)       // 8192
#define OFF_PART  (OFF_W1TT + 8192)         // 270336
#define OFF_RED   (OFF_PART + 270336)       // 136
#define OFF_WAW   (OFF_RED + 136)           // [3][2 taps][128][64] bf16 = 24576 floats
#define OFF_SWW   (OFF_WAW + 24576)         // [3][64][64] bf16 = 6144
#define OFF_WSTW  (OFF_SWW + 6144)          // [64][64] bf16 (K=64, k<16 real) = 2048

// chunk-XOR swizzle on the k dimension (8-bf16 chunks within 64-k tiles)
#define SWZK(k, x) (((k) & ~63) | (((((k) >> 3) & 7) ^ ((x) & 7)) << 3) | ((k) & 7))
// gbuf row swizzle (8 chunks/row)
#define GSWZ(n) ((((n) >> 3) ^ (n)) & 7)

typedef __attribute__((ext_vector_type(8))) short short8;
typedef __attribute__((ext_vector_type(4))) float f32x4;
typedef const __attribute__((address_space(1))) uint32_t* gas_t;
typedef __attribute__((address_space(3))) uint32_t* las_t;

__device__ __forceinline__ float fast_rcp(float x) { return __builtin_amdgcn_rcpf(x); }
__device__ __forceinline__ float fast_tanh(float x) {
    x = fminf(fmaxf(x, -10.f), 10.f);
    float e = __expf(2.f * x);
    return (e - 1.f) * fast_rcp(e + 1.f);
}
__device__ __forceinline__ float fast_sigmoid(float x) {
    return fast_rcp(1.f + __expf(-x));
}
// RNE f32->bf16 (proven bit-path; v_cvt_pk_bf16_f32 regressed absmax 13x in r8)
__device__ __forceinline__ unsigned short f2bf(float f) {
    uint32_t u = __float_as_uint(f);
    u += 0x7fff + ((u >> 16) & 1);
    return (unsigned short)(u >> 16);
}
__device__ __forceinline__ float bf2f(unsigned short b) {
    return __uint_as_float(((uint32_t)b) << 16);
}

// ---------------- K0: precompute (parallelized over 64 blocks) ----------------
__global__ __launch_bounds__(256) void prep_kernel(const float* __restrict__ gcn_w,
                            const float* __restrict__ h0_w1, const float* __restrict__ h0_b1,
                            const float* __restrict__ h1_w1, const float* __restrict__ h1_b1,
                            const float* __restrict__ task_emb,
                            const float* __restrict__ filt_w, const float* __restrict__ gate_w,
                            const float* __restrict__ skip_w, const float* __restrict__ start_w,
                            float* __restrict__ c01, float* __restrict__ wgcnT,
                            float* __restrict__ w1tT,
                            unsigned short* __restrict__ waw,
                            unsigned short* __restrict__ sww,
                            unsigned short* __restrict__ wstw)
{
    const int GS = 64 * 256;
    int gt = blockIdx.x * 256 + threadIdx.x;
    for (int idx = gt; idx < 64 * 192; idx += GS) {
        int o = idx / 192, j = idx % 192;
        wgcnT[j * 64 + o] = gcn_w[idx];
    }
    for (int idx = gt; idx < 4096; idx += GS) {
        int o = idx >> 6, c = idx & 63;
        w1tT[c * 64 + o]        = h0_w1[o * 128 + 64 + c];
        w1tT[4096 + c * 64 + o] = h1_w1[o * 128 + 64 + c];
    }
    // WA[L][p][r][k=c]: r<64 filt row r, r>=64 gate row r-64; tap p; chunk-swizzled ^(r&7)
    for (int job = gt; job < 3 * 2 * 128 * 8; job += GS) {
        int L = job / 2048, rem = job % 2048;
        int p = rem >> 10, rem2 = rem & 1023;
        int r = rem2 >> 3, chp = rem2 & 7;
        int cho = chp ^ (r & 7);
        #pragma unroll
        for (int i = 0; i < 8; ++i) {
            int c = cho * 8 + i;
            float v = (r < 64) ? filt_w[L * 8192 + r * 128 + c * 2 + p]
                               : gate_w[L * 8192 + (r - 64) * 128 + c * 2 + p];
            waw[((L * 2 + p) * 128 + r) * 64 + chp * 8 + i] = f2bf(v);
        }
    }
    for (int job = gt; job < 3 * 64 * 8; job += GS) {
        int L = job / 512, rem = job % 512;
        int r = rem >> 3, chp = rem & 7;
        int cho = chp ^ (r & 7);
        #pragma unroll
        for (int i = 0; i < 8; ++i)
            sww[(L * 64 + r) * 64 + chp * 8 + i] = f2bf(skip_w[L * 4096 + r * 64 + cho * 8 + i]);
    }
    // start W: [64 r][64 k] (k<16 real), chunk-swizzled ^(r&7)
    for (int job = gt; job < 64 * 8; job += GS) {
        int r = job >> 3, chp = job & 7;
        int cho = chp ^ (r & 7);
        #pragma unroll
        for (int i = 0; i < 8; ++i) {
            int k = cho * 8 + i;
            wstw[r * 64 + chp * 8 + i] = (k < 16) ? f2bf(start_w[r * 16 + k]) : (unsigned short)0;
        }
    }
    if (gt < 128) {
        int head = gt >> 6, o = gt & 63;
        const float* w1 = head ? h1_w1 : h0_w1;
        const float* b1 = head ? h1_b1 : h0_b1;
        float a = b1[o];
        for (int k = 0; k < 64; ++k) a = fmaf(w1[o * 128 + k], task_emb[k], a);
        c01[gt] = a;
    }
}

// ---------------- K1: adpF = softmax(relu(nv1@nv2), axis=1), fp32, coalesced ----------------
__global__ __launch_bounds__(256) void adp_kernel(const float* __restrict__ nv1,
                                                  const float* __restrict__ nv2,
                                                  float* __restrict__ adpF)
{
    __shared__ float nv1s[10];
    __shared__ float rbuf[4];
    int tid = threadIdx.x;
    int r = blockIdx.x;
    if (tid < 10) nv1s[tid] = nv1[r * 10 + tid];
    __syncthreads();

    float val[8];
    float vmax = -3.4e38f;
    #pragma unroll
    for (int s = 0; s < 8; ++s) {
        int j = tid + s * 256;
        if (j < NN) {
            float v = 0.f;
            #pragma unroll
            for (int k = 0; k < 10; ++k) v = fmaf(nv1s[k], nv2[k * NN + j], v);
            v = fmaxf(v, 0.f);
            val[s] = v;
            vmax = fmaxf(vmax, v);
        } else val[s] = -3.4e38f;
    }
    for (int off = 32; off; off >>= 1) vmax = fmaxf(vmax, __shfl_down(vmax, off, 64));
    if ((tid & 63) == 0) rbuf[tid >> 6] = vmax;
    __syncthreads();
    vmax = fmaxf(fmaxf(rbuf[0], rbuf[1]), fmaxf(rbuf[2], rbuf[3]));
    __syncthreads();
    float sum = 0.f;
    #pragma unroll
    for (int s = 0; s < 8; ++s) {
        int j = tid + s * 256;
        if (j < NN) { val[s] = expf(val[s] - vmax); sum += val[s]; }
    }
    for (int off = 32; off; off >>= 1) sum += __shfl_down(sum, off, 64);
    if ((tid & 63) == 0) rbuf[tid >> 6] = sum;
    __syncthreads();
    sum = rbuf[0] + rbuf[1] + rbuf[2] + rbuf[3];
    float inv = 1.f / sum;
    #pragma unroll
    for (int s = 0; s < 8; ++s) {
        int j = tid + s * 256;
        if (j < NN) adpF[(size_t)r * NPAD + j] = val[s] * inv;
    }
}

// ---------------- K1b: adpT = transpose(adpF) -> bf16, k-swizzled, zero-padded ----------------
__global__ __launch_bounds__(256) void transpose_adp(const float* __restrict__ adpF,
                                                     unsigned short* __restrict__ adpT)
{
    __shared__ float tile[64][65];
    int tid = threadIdx.x;
    int r0 = blockIdx.x * 64;
    int j0 = blockIdx.y * 64;
    #pragma unroll
    for (int s = 0; s < 16; ++s) {
        int idx = s * 256 + tid;
        int i = idx >> 6, jj = idx & 63;
        int r = r0 + i, j = j0 + jj;
        tile[i][jj] = (r < NN && j < NN) ? adpF[(size_t)r * NPAD + j] : 0.f;
    }
    __syncthreads();
    #pragma unroll
    for (int s = 0; s < 2; ++s) {
        int slot = s * 256 + tid;
        int j = slot >> 3, ch = slot & 7;
        short8 v;
        #pragma unroll
        for (int e = 0; e < 8; ++e) v[e] = (short)f2bf(tile[ch * 8 + e][j]);
        *(short8*)&adpT[(size_t)(j0 + j) * NPAD + r0 + ((ch ^ (j & 7)) << 3)] = v;
    }
}

// ---------------- K2: fused temporal stack (MFMA, tapless xb, 32 items/block) ----------------
// LDS (105.5 KB): xb[256 rows n=g*8+t][64 k=c] (32KB), gbuf[256][64] (32KB),
//   WA[2 taps][128][64] per-layer (32KB), SW[64][64] per-layer (8KB), bias (1.5KB).
// Conv = two K=64 MFMA chains (tap0 row n, tap1 row n+D) in the old kstep order
// -> bit-identical to the K=128 duplicated-tap version (verified r11).
template<int NG, int WOUT, int D>
__device__ __forceinline__ void mfma_phaseB(int L,
    const unsigned short* __restrict__ xb, unsigned short* __restrict__ gbuf,
    const unsigned short* __restrict__ WA, const float* __restrict__ biasAll,
    int wave, int lr, int lk)
{
    if (wave >= NG) return;
    int idx = wave * 16 + lr;
    int n = (idx / WOUT) * 8 + (idx % WOUT);
    f32x4 aF[4], aG[4];
    #pragma unroll
    for (int mt = 0; mt < 4; ++mt) {
        aF[mt] = (f32x4){0.f, 0.f, 0.f, 0.f};
        aG[mt] = (f32x4){0.f, 0.f, 0.f, 0.f};
    }
    #pragma unroll
    for (int p = 0; p < 2; ++p) {
        int nb = n + p * D;
        const unsigned short* WAp = WA + p * 8192;
        #pragma unroll
        for (int ks = 0; ks < 2; ++ks) {
            short8 bv = *(const short8*)&xb[(nb * 8 + ((ks * 4 + lk) ^ (nb & 7))) * 8];
            #pragma unroll
            for (int mt = 0; mt < 4; ++mt) {
                int r = mt * 16 + lr;
                short8 av = *(const short8*)&WAp[(r * 8 + ((ks * 4 + lk) ^ (r & 7))) * 8];
                aF[mt] = __builtin_amdgcn_mfma_f32_16x16x32_bf16(av, bv, aF[mt], 0, 0, 0);
            }
            #pragma unroll
            for (int mt = 0; mt < 4; ++mt) {
                int r = (mt + 4) * 16 + lr;
                short8 av = *(const short8*)&WAp[(r * 8 + ((ks * 4 + lk) ^ (r & 7))) * 8];
                aG[mt] = __builtin_amdgcn_mfma_f32_16x16x32_bf16(av, bv, aG[mt], 0, 0, 0);
            }
        }
    }
    int gs = GSWZ(n);
    #pragma unroll
    for (int mt = 0; mt < 4; ++mt) {
        int ob = mt * 16 + lk * 4;
        ushort4 p;
        p.x = f2bf(fast_tanh(aF[mt][0] + biasAll[L * 128 + ob + 0]) * fast_sigmoid(aG[mt][0] + biasAll[L * 128 + 64 + ob + 0]));
        p.y = f2bf(fast_tanh(aF[mt][1] + biasAll[L * 128 + ob + 1]) * fast_sigmoid(aG[mt][1] + biasAll[L * 128 + 64 + ob + 1]));
        p.z = f2bf(fast_tanh(aF[mt][2] + biasAll[L * 128 + ob + 2]) * fast_sigmoid(aG[mt][2] + biasAll[L * 128 + 64 + ob + 2]));
        p.w = f2bf(fast_tanh(aF[mt][3] + biasAll[L * 128 + ob + 3]) * fast_sigmoid(aG[mt][3] + biasAll[L * 128 + 64 + ob + 3]));
        *(ushort4*)&gbuf[((n * 8) + ((mt * 2 + (lk >> 1)) ^ gs)) * 8 + (lk & 1) * 4] = p;
    }
}

// wave handles 2 items (g = wave*2+gi); writes each x value ONCE (tapless xb).
template<int L, int D, int WOUT>
__device__ __forceinline__ void phaseC_conv(unsigned short* __restrict__ xb,
    const unsigned short* __restrict__ gbuf,
    const float* __restrict__ bn_g, const float* __restrict__ bn_b,
    float xreg[2][8], int wave, int o)
{
    float bsc = bn_g[L * 64 + o] * rsqrtf(1.0f + 1e-5f);
    float bsh = bn_b[L * 64 + o];
    #pragma unroll
    for (int gi = 0; gi < 2; ++gi) {
        int g = wave * 2 + gi;
        #pragma unroll
        for (int t = 0; t < WOUT; ++t) {
            int n = g * 8 + t;
            float gv = bf2f(gbuf[(n * 8 + ((o >> 3) ^ GSWZ(n))) * 8 + (o & 7)]);
            float nx = (gv + xreg[gi][t + D]) * bsc + bsh;
            xreg[gi][t] = nx;
            xb[(n * 8 + ((o >> 3) ^ (n & 7))) * 8 + (o & 7)] = f2bf(nx);
        }
    }
}

__device__ __forceinline__ void phaseC_skip(int LASTT,
    const unsigned short* __restrict__ gbuf, const unsigned short* __restrict__ SW,
    f32x4 skacc[4], int wave, int lr, int lk)
{
    if (wave >= 2) return;
    int g = wave * 16 + lr;
    int n = g * 8 + LASTT;
    int gs = GSWZ(n);
    #pragma unroll
    for (int ks = 0; ks < 2; ++ks) {
        short8 bv = *(const short8*)&gbuf[(n * 8 + ((ks * 4 + lk) ^ gs)) * 8];
        #pragma unroll
        for (int mt = 0; mt < 4; ++mt) {
            int r = mt * 16 + lr;
            short8 av = *(const short8*)&SW[(r * 8 + ((ks * 4 + lk) ^ (r & 7))) * 8];
            skacc[mt] = __builtin_amdgcn_mfma_f32_16x16x32_bf16(av, bv, skacc[mt], 0, 0, 0);
        }
    }
}

__global__ __launch_bounds__(1024) void temporal_kernel(
    const float* __restrict__ X,
    const float* __restrict__ start_b,
    const unsigned short* __restrict__ waw,
    const unsigned short* __restrict__ sww,
    const unsigned short* __restrict__ wstw,
    const float* __restrict__ filt_b, const float* __restrict__ gate_b,
    const float* __restrict__ skip_b,
    const float* __restrict__ bn_g, const float* __restrict__ bn_b,
    float* __restrict__ S, unsigned short* __restrict__ St)
{
    extern __shared__ float smem[];
    unsigned short* xb   = (unsigned short*)smem;              // 16384 ush [256][64]
    unsigned short* gbuf = (unsigned short*)(smem + 8192);     // 16384 ush [256][64]
    unsigned short* WA   = (unsigned short*)(smem + 16384);    // 16384 ush (2 taps x 128 x 64)
    unsigned short* SW   = (unsigned short*)(smem + 24576);    // 4096 ush
    float* biasAll       = smem + 26624;                       // 384 f32

    int tid = threadIdx.x;
    int wave = tid >> 6, lane = tid & 63;
    int lr = lane & 15, lk = lane >> 4;
    int o = lane;
    int item0 = blockIdx.x * 32;

    // ---- init: stage start-W into WA rows 0..63, bias, X -> xb ----
    if (tid < 512)
        __builtin_amdgcn_global_load_lds((gas_t)(wstw + tid * 8), (las_t)(WA + tid * 8), 16, 0, 0);
    if (tid < 384) {
        int L = tid >> 7, oo = tid & 127;
        biasAll[tid] = (oo < 64) ? filt_b[L * 64 + oo] : gate_b[L * 64 + oo - 64];
    }
    // X -> xb: 256 rows x 8 chunks = 2048 slots over 1024 threads (2 iters)
    #pragma unroll
    for (int s = 0; s < 2; ++s) {
        int idx = s * 1024 + tid;
        int n = idx >> 3, c = idx & 7;
        int g = n >> 3, t = n & 7;
        int ig = item0 + g, b = ig / NN, nn = ig - b * NN;
        int cho = c ^ (n & 7);
        short8 v = {0, 0, 0, 0, 0, 0, 0, 0};
        if (cho < 2) {
            const float* src = &X[((size_t)(b * TT + t) * NN + nn) * NF + cho * 8];
            float4 f0 = *(const float4*)src;
            float4 f1 = *(const float4*)(src + 4);
            v[0] = (short)f2bf(f0.x); v[1] = (short)f2bf(f0.y);
            v[2] = (short)f2bf(f0.z); v[3] = (short)f2bf(f0.w);
            v[4] = (short)f2bf(f1.x); v[5] = (short)f2bf(f1.y);
            v[6] = (short)f2bf(f1.z); v[7] = (short)f2bf(f1.w);
        }
        *(short8*)&xb[(n * 8 + c) * 8] = v;
    }
    __syncthreads();

    // ---- start conv MFMA (K=32: chunk lk only; 256 rows via 16 waves) + stage SW L0 ----
    {
        f32x4 aS[4];
        #pragma unroll
        for (int mt = 0; mt < 4; ++mt) aS[mt] = (f32x4){0.f, 0.f, 0.f, 0.f};
        int n = wave * 16 + lr;
        short8 bv = *(const short8*)&xb[(n * 8 + (lk ^ (n & 7))) * 8];
        #pragma unroll
        for (int mt = 0; mt < 4; ++mt) {
            int r = mt * 16 + lr;
            short8 av = *(const short8*)&WA[(r * 8 + (lk ^ (r & 7))) * 8];
            aS[mt] = __builtin_amdgcn_mfma_f32_16x16x32_bf16(av, bv, aS[mt], 0, 0, 0);
        }
        int gs = GSWZ(n);
        #pragma unroll
        for (int mt = 0; mt < 4; ++mt) {
            ushort4 p;
            p.x = f2bf(aS[mt][0]); p.y = f2bf(aS[mt][1]);
            p.z = f2bf(aS[mt][2]); p.w = f2bf(aS[mt][3]);
            *(ushort4*)&gbuf[((n * 8) + ((mt * 2 + (lk >> 1)) ^ gs)) * 8 + (lk & 1) * 4] = p;
        }
    }
    if (tid < 512)
        __builtin_amdgcn_global_load_lds((gas_t)(sww + tid * 8), (las_t)(SW + tid * 8), 16, 0, 0);
    __syncthreads();

    float xreg[2][8];
    f32x4 skacc[4];
    #pragma unroll
    for (int mt = 0; mt < 4; ++mt) skacc[mt] = (f32x4){0.f, 0.f, 0.f, 0.f};

    // ---- C0: x = start_out + start_b (wave -> 2 items); write all 8 rows; stage WA L0 ----
    {
        __builtin_amdgcn_global_load_lds((gas_t)(waw + (size_t)tid * 8),
                                         (las_t)(WA + tid * 8), 16, 0, 0);
        __builtin_amdgcn_global_load_lds((gas_t)(waw + (size_t)(tid + 1024) * 8),
                                         (las_t)(WA + (tid + 1024) * 8), 16, 0, 0);
        float sb = start_b[o];
        #pragma unroll
        for (int gi = 0; gi < 2; ++gi) {
            int g = wave * 2 + gi;
            #pragma unroll
            for (int t = 0; t < 8; ++t) {
                int n = g * 8 + t;
                float gv = bf2f(gbuf[(n * 8 + ((o >> 3) ^ GSWZ(n))) * 8 + (o & 7)]) + sb;
                xreg[gi][t] = gv;
                xb[(n * 8 + ((o >> 3) ^ (n & 7))) * 8 + (o & 7)] = f2bf(gv);
            }
        }
    }
    __syncthreads();

    // ---- B0 (live t<7: 224 rows = 14 groups) ----
    mfma_phaseB<14, 7, 1>(0, xb, gbuf, WA, biasAll, wave, lr, lk);
    __syncthreads();
    // ---- PC0: skip(0) + conv(0) + stage WA L1 ----
    phaseC_skip(6, gbuf, SW, skacc, wave, lr, lk);
    phaseC_conv<0, 1, 7>(xb, gbuf, bn_g, bn_b, xreg, wave, o);
    __builtin_amdgcn_global_load_lds((gas_t)(waw + (size_t)(16384 + tid * 8)),
                                     (las_t)(WA + tid * 8), 16, 0, 0);
    __builtin_amdgcn_global_load_lds((gas_t)(waw + (size_t)(16384 + (tid + 1024) * 8)),
                                     (las_t)(WA + (tid + 1024) * 8), 16, 0, 0);
    __syncthreads();

    // ---- B1 (live t<5: 160 rows = 10 groups) + stage SW L1 ----
    mfma_phaseB<10, 5, 2>(1, xb, gbuf, WA, biasAll, wave, lr, lk);
    if (tid < 512)
        __builtin_amdgcn_global_load_lds((gas_t)(sww + (size_t)(4096 + tid * 8)),
                                         (las_t)(SW + tid * 8), 16, 0, 0);
    __syncthreads();
    // ---- PC1: skip(1) + conv(1) + stage WA L2 ----
    phaseC_skip(4, gbuf, SW, skacc, wave, lr, lk);
    phaseC_conv<1, 2, 5>(xb, gbuf, bn_g, bn_b, xreg, wave, o);
    __builtin_amdgcn_global_load_lds((gas_t)(waw + (size_t)(32768 + tid * 8)),
                                     (las_t)(WA + tid * 8), 16, 0, 0);
    __builtin_amdgcn_global_load_lds((gas_t)(waw + (size_t)(32768 + (tid + 1024) * 8)),
                                     (las_t)(WA + (tid + 1024) * 8), 16, 0, 0);
    __syncthreads();

    // ---- B2 (live t<1: 32 rows = 2 groups) + stage SW L2 ----
    mfma_phaseB<2, 1, 4>(2, xb, gbuf, WA, biasAll, wave, lr, lk);
    if (tid < 512)
        __builtin_amdgcn_global_load_lds((gas_t)(sww + (size_t)(8192 + tid * 8)),
                                         (las_t)(SW + tid * 8), 16, 0, 0);
    __syncthreads();
    // ---- PC2: skip(2) ----
    phaseC_skip(0, gbuf, SW, skacc, wave, lr, lk);

    // ---- final skip writes (waves 0,1 hold skip[o][g] for 32 items) ----
    if (wave < 2) {
        int g = wave * 16 + lr;
        int ig = item0 + g, b = ig / NN, nn = ig - b * NN;
        #pragma unroll
        for (int mt = 0; mt < 4; ++mt) {
            #pragma unroll
            for (int j = 0; j < 4; ++j) {
                int oo = mt * 16 + lk * 4 + j;
                float v = skacc[mt][j] + skip_b[oo] + skip_b[64 + oo] + skip_b[128 + oo];
                int bc = b * 64 + oo;
                S[(size_t)nn * BCD + bc] = v;
                St[(size_t)bc * NPAD + SWZK(nn, oo)] = f2bf(v);
            }
        }
    }
}

// ---------------- K3: bf16 MFMA GEMM, C[m][n] = sum_k A[m][k]*B[n][k] ----------------
// 1-D grid of 512 blocks; XCD-aware bijective swizzle (T1): lid' = (lid%8)*64 + lid/8.
__global__ __launch_bounds__(256) void gemm_mfma(
    const unsigned short* __restrict__ A, const unsigned short* __restrict__ B,
    float* __restrict__ Cf, unsigned short* __restrict__ Ct)
{
    __shared__ unsigned short As[128 * 64];
    __shared__ unsigned short Bs[128 * 64];
    int tid = threadIdx.x;
    int wave = tid >> 6, lane = tid & 63;
    int lk = lane >> 4, lr = lane & 15;
    int lid = blockIdx.x;
    int lid2 = (lid & 7) * 64 + (lid >> 3);   // 512 blocks, %8==0 -> bijective
    int bx = lid2 & 31, by = lid2 >> 5;
    int n0 = bx * 128, m0 = by * 128;
    int wm = wave >> 1, wn = wave & 1;

    f32x4 acc[4][4];
    #pragma unroll
    for (int i = 0; i < 4; ++i)
        #pragma unroll
        for (int j = 0; j < 4; ++j)
            acc[i][j] = (f32x4){0.f, 0.f, 0.f, 0.f};

    for (int k0 = 0; k0 < NPAD; k0 += 64) {
        #pragma unroll
        for (int i = 0; i < 4; ++i) {
            int chunk = wave * 4 + i;
            int row = chunk * 8 + (lane >> 3);
            int koff = (lane & 7) * 8;
            __builtin_amdgcn_global_load_lds(
                (gas_t)(A + (size_t)(m0 + row) * NPAD + k0 + koff),
                (las_t)(&As[chunk * 512]), 16, 0, 0);
            __builtin_amdgcn_global_load_lds(
                (gas_t)(B + (size_t)(n0 + row) * NPAD + k0 + koff),
                (las_t)(&Bs[chunk * 512]), 16, 0, 0);
        }
        __syncthreads();
        #pragma unroll
        for (int s = 0; s < 2; ++s) {
            short8 av[4], bv[4];
            #pragma unroll
            for (int f = 0; f < 4; ++f) {
                int m = wm * 64 + f * 16 + lr;
                int ca = ((s * 4 + lk) ^ (m & 7));
                av[f] = *(const short8*)&As[m * 64 + ca * 8];
                int n = wn * 64 + f * 16 + lr;
                int cb = ((s * 4 + lk) ^ (n & 7));
                bv[f] = *(const short8*)&Bs[n * 64 + cb * 8];
            }
            #pragma unroll
            for (int fi = 0; fi < 4; ++fi)
                #pragma unroll
                for (int fj = 0; fj < 4; ++fj)
                    acc[fi][fj] = __builtin_amdgcn_mfma_f32_16x16x32_bf16(
                        av[fi], bv[fj], acc[fi][fj], 0, 0, 0);
        }
        __syncthreads();
    }

    #pragma unroll
    for (int fi = 0; fi < 4; ++fi) {
        #pragma unroll
        for (int fj = 0; fj < 4; ++fj) {
            int m = m0 + wm * 64 + fi * 16 + lk * 4;
            int n = n0 + wn * 64 + fj * 16 + lr;
            f32x4 v = acc[fi][fj];
            if (Cf) {
                Cf[(size_t)(m + 0) * BCD + n] = v[0];
                Cf[(size_t)(m + 1) * BCD + n] = v[1];
                Cf[(size_t)(m + 2) * BCD + n] = v[2];
                Cf[(size_t)(m + 3) * BCD + n] = v[3];
            }
            if (Ct) {
                ushort4 p;
                p.x = f2bf(v[0]); p.y = f2bf(v[1]);
                p.z = f2bf(v[2]); p.w = f2bf(v[3]);
                *(ushort4*)&Ct[(size_t)n * NPAD + SWZK(m, n)] = p;
            }
        }
    }
}

// ---------------- K4: gcn 1x1 + heads + outputs + partial reductions ----------------
__global__ __launch_bounds__(256) void head_kernel(
    const float* __restrict__ S, const float* __restrict__ x1f,
    const float* __restrict__ x2,
    const float* __restrict__ wgcnT, const float* __restrict__ gcn_b,
    const float* __restrict__ c01, const float* __restrict__ w1tT,
    const float* __restrict__ h0_w2, const float* __restrict__ h0_b2,
    const float* __restrict__ h1_w2, const float* __restrict__ h1_b2,
    const int* __restrict__ Ct, const float* __restrict__ Yf,
    float* __restrict__ out, float* __restrict__ partials)
{
    __shared__ float hl[4][4][192];
    __shared__ float gxl[4][4][64];
    int tid = threadIdx.x;
    int wave = tid >> 6, o = tid & 63;
    int wid = blockIdx.x * 4 + wave;
    float w2a = h0_w2[o], w2b = h1_w2[o];
    float b20 = h0_b2[0], b21 = h1_b2[0];
    float cb = gcn_b[o], c0a = c01[o], c0b = c01[64 + o];

    float accT = 0.f, accC = 0.f, bce = 0.f, cT = 0.f, cC = 0.f;

    for (int base = wid * 4; base < ITEMS; base += 2048 * 4) {
        #pragma unroll
        for (int it = 0; it < 4; ++it) {
            int item = base + it;
            int b = item / NN, n = item - b * NN;
            int bc = b * 64 + o;
            hl[wave][it][o]       = S[(size_t)n * BCD + bc];
            hl[wave][it][64 + o]  = x1f[(size_t)n * BCD + bc];
            hl[wave][it][128 + o] = x2[(size_t)n * BCD + bc];
        }
        float a0 = cb, a1 = cb, a2 = cb, a3 = cb;
        for (int j = 0; j < 192; ++j) {
            float w = wgcnT[j * 64 + o];
            a0 = fmaf(w, hl[wave][0][j], a0);
            a1 = fmaf(w, hl[wave][1][j], a1);
            a2 = fmaf(w, hl[wave][2][j], a2);
            a3 = fmaf(w, hl[wave][3][j], a3);
        }
        float gxv[4] = {fmaxf(a0, 0.f), fmaxf(a1, 0.f), fmaxf(a2, 0.f), fmaxf(a3, 0.f)};
        #pragma unroll
        for (int it = 0; it < 4; ++it) gxl[wave][it][o] = gxv[it];

        float p0[4], p1[4];
        #pragma unroll
        for (int it = 0; it < 4; ++it) { p0[it] = c0a; p1[it] = c0b; }
        for (int c = 0; c < 64; ++c) {
            float w0 = w1tT[c * 64 + o];
            float w1 = w1tT[4096 + c * 64 + o];
            float g0 = gxl[wave][0][c], g1 = gxl[wave][1][c];
            float g2 = gxl[wave][2][c], g3 = gxl[wave][3][c];
            p0[0] = fmaf(w0, g0, p0[0]); p0[1] = fmaf(w0, g1, p0[1]);
            p0[2] = fmaf(w0, g2, p0[2]); p0[3] = fmaf(w0, g3, p0[3]);
            p1[0] = fmaf(w1, g0, p1[0]); p1[1] = fmaf(w1, g1, p1[1]);
            p1[2] = fmaf(w1, g2, p1[2]); p1[3] = fmaf(w1, g3, p1[3]);
        }
        #pragma unroll
        for (int it = 0; it < 4; ++it) {
            float r0 = w2a * fmaxf(p0[it], 0.f);
            float r1 = w2b * fmaxf(p1[it], 0.f);
            #pragma unroll
            for (int off = 32; off; off >>= 1) {
                r0 += __shfl_down(r0, off, 64);
                r1 += __shfl_down(r1, off, 64);
            }
            int item = base + it;
            int tt = Ct[item];
            if (o == 0) {
                float y0 = 1.f / (1.f + expf(-(r0 + b20)));
                float y1 = 1.f / (1.f + expf(-(r1 + b21)));
                float y = (tt > 0) ? y1 : y0;
                out[1 + item] = y;
                out[1 + ITEMS + item] = y0;
                out[1 + 2 * ITEMS + item] = y1;
                float yc = fminf(fmaxf(y, 1e-7f), 1.f - 1e-7f);
                float Yv = Yf[item];
                bce -= Yv * logf(yc) + (1.f - Yv) * logf(1.f - yc);
                if (tt > 0) cT += 1.f; else cC += 1.f;
            }
            if (tt > 0) accT += gxv[it]; else accC += gxv[it];
        }
    }
    partials[wid * 132 + o] = accT;
    partials[wid * 132 + 64 + o] = accC;
    if (o == 0) {
        partials[wid * 132 + 128] = bce;
        partials[wid * 132 + 129] = cT;
        partials[wid * 132 + 130] = cC;
    }
}

// ---------------- K5a: parallel slot reduce ----------------
__global__ __launch_bounds__(256) void reduce_kernel(const float* __restrict__ partials,
                                                     float* __restrict__ red)
{
    __shared__ float rb[4];
    int slot = blockIdx.x;
    int tid = threadIdx.x;
    float s = 0.f;
    for (int w = tid; w < 2048; w += 256) s += partials[w * 132 + slot];
    #pragma unroll
    for (int off = 32; off; off >>= 1) s += __shfl_down(s, off, 64);
    if ((tid & 63) == 0) rb[tid >> 6] = s;
    __syncthreads();
    if (tid == 0) red[slot] = rb[0] + rb[1] + rb[2] + rb[3];
}

// ---------------- K5b: final loss ----------------
__global__ void final_kernel(const float* __restrict__ red,
                             const float* __restrict__ task_emb,
                             float* __restrict__ out)
{
    int tid = threadIdx.x; // 64
    float cT = red[129], cC = red[130];
    float iT = 1.f / fmaxf(cT, 1.f), iC = 1.f / fmaxf(cC, 1.f);
    float d1 = task_emb[tid] * (cT * iT) - task_emb[tid] * (cC * iC);
    float d2 = red[tid] * iT - red[64 + tid] * iC;
    float p = d1 * d1 + d2 * d2;
    #pragma unroll
    for (int off = 32; off; off >>= 1) p += __shfl_down(p, off, 64);
    if (tid == 0) out[0] = red[128] * (1.f / (float)ITEMS) + p;
}

// ---------------- launch ----------------
extern "C" void kernel_launch(void* const* d_in, const int* in_sizes, int n_in,
                              void* d_out, int out_size, void* d_ws, size_t ws_size,
                              hipStream_t stream)
{
    const float* X       = (const float*)d_in[0];
    const int*   Ct      = (const int*)d_in[2];
    const float* Yf      = (const float*)d_in[3];
    const float* start_w = (const float*)d_in[5];
    const float* start_b = (const float*)d_in[6];
    const float* filt_w  = (const float*)d_in[7];
    const float* filt_b  = (const float*)d_in[8];
    const float* gate_w  = (const float*)d_in[9];
    const float* gate_b  = (const float*)d_in[10];
    const float* skip_w  = (const float*)d_in[11];
    const float* skip_b  = (const float*)d_in[12];
    const float* bn_g    = (const float*)d_in[13];
    const float* bn_b    = (const float*)d_in[14];
    const float* nv1     = (const float*)d_in[15];
    const float* nv2     = (const float*)d_in[16];
    const float* task    = (const float*)d_in[17];
    const float* gcn_w   = (const float*)d_in[18];
    const float* gcn_b   = (const float*)d_in[19];
    const float* h0_w1   = (const float*)d_in[20];
    const float* h0_b1   = (const float*)d_in[21];
    const float* h0_w2   = (const float*)d_in[22];
    const float* h0_b2   = (const float*)d_in[23];
    const float* h1_w1   = (const float*)d_in[24];
    const float* h1_b1   = (const float*)d_in[25];
    const float* h1_w2   = (const float*)d_in[26];
    const float* h1_b2   = (const float*)d_in[27];

    float* ws    = (float*)d_ws;
    float* adpF  = ws + OFF_ADPF;
    unsigned short* St   = (unsigned short*)(ws + OFF_ST);
    float* x2    = ws + OFF_X2;        // aliases [adpF|St], safe by schedule
    unsigned short* adpT = (unsigned short*)(ws + OFF_ADPT);
    float* S     = ws + OFF_S;
    float* x1f   = ws + OFF_X1F;
    unsigned short* x1t  = (unsigned short*)(ws + OFF_X1T);
    float* c01   = ws + OFF_C01;
    float* wgcnT = ws + OFF_WGCNT;
    float* w1tT  = ws + OFF_W1TT;
    float* part  = ws + OFF_PART;
    float* red   = ws + OFF_RED;
    unsigned short* waw  = (unsigned short*)(ws + OFF_WAW);
    unsigned short* sww  = (unsigned short*)(ws + OFF_SWW);
    unsigned short* wstw = (unsigned short*)(ws + OFF_WSTW);
    float* outp  = (float*)d_out;

    // zero St (pad columns n in [2000,2048) must contribute 0 to GEMM1)
    hipMemsetAsync(St, 0, (size_t)BCD * NPAD * sizeof(unsigned short), stream);

    prep_kernel<<<64, 256, 0, stream>>>(gcn_w, h0_w1, h0_b1, h1_w1, h1_b1, task,
                                        filt_w, gate_w, skip_w, start_w,
                                        c01, wgcnT, w1tT, waw, sww, wstw);
    adp_kernel<<<NN, 256, 0, stream>>>(nv1, nv2, adpF);
    dim3 tg(NPAD / 64, NPAD / 64);
    transpose_adp<<<tg, 256, 0, stream>>>(adpF, adpT);

    const int K2_LDS = 27008 * 4; // 105.5 KiB dynamic LDS
    hipFuncSetAttribute(reinterpret_cast<const void*>(temporal_kernel),
                        hipFuncAttributeMaxDynamicSharedMemorySize, K2_LDS);
    temporal_kernel<<<ITEMS / 32, 1024, K2_LDS, stream>>>(
        X, start_b, waw, sww, wstw, filt_b, gate_b,
        skip_b, bn_g, bn_b, S, St);

    gemm_mfma<<<512, 256, 0, stream>>>(adpT, St, x1f, x1t);      // x1 (both layouts)
    gemm_mfma<<<512, 256, 0, stream>>>(adpT, x1t, x2, nullptr);  // x2 = adp^T·x1

    head_kernel<<<512, 256, 0, stream>>>(S, x1f, x2, wgcnT, gcn_b, c01, w1tT,
                                         h0_w2, h0_b2, h1_w2, h1_b2,
                                         Ct, Yf, outp, part);
    reduce_kernel<<<131, 256, 0, stream>>>(part, red);
    final_kernel<<<1, 64, 0, stream>>>(red, task, outp);
}

// Round 13
// 531.853 us; speedup vs baseline: 1.1829x; 1.0228x over previous
//
#include <hip/hip_runtime.h>
#include <cstdint>

// ---------------- problem constants ----------------
#define NB 64        // batch
#define TT 8         // timesteps
#define NN 2000      // nodes
#define NF 16        // in features
#define NCH 64       // channels
#define NPAD 2048    // padded node dim
#define BCD 4096     // NB*NCH
#define ITEMS 128000 // NB*NN

// ws offsets (floats). x2 aliases [adpF|St] (both dead before GEMM2 writes x2).
#define OFF_ADPF  0                         // fp32 adp [2048][2048] = 4194304
#define OFF_ST    4194304                   // bf16 St [4096][2048]  = 4194304 floats
#define OFF_X2    0                         // fp32 x2 [2048][4096]  = 8388608 (alias)
#define OFF_ADPT  8388608                   // bf16 adpT [2048][2048] = 2097152 floats
#define OFF_S     10485760                  // fp32 S [2048][4096]   = 8388608
#define OFF_X1F   18874368                  // fp32 x1 [2048][4096]  = 8388608
#define OFF_X1T   27262976                  // bf16 x1t [4096][2048] = 4194304 floats
#define OFF_C01   31457280                  // 128
#define OFF_WGCNT (OFF_C01 + 128)           // 12288
#define OFF_W1TT  (OFF_WGCNT + 12288)       // 8192
#define OFF_PART  (OFF_W1TT + 8192)         // 270336
#define OFF_RED   (OFF_PART + 270336)       // 136
#define OFF_WAW   (OFF_RED + 136)           // [3][128][128] bf16 (dup-tap, 16ch) = 24576
#define OFF_SWW   (OFF_WAW + 24576)         // [3][64][64] bf16 = 6144
#define OFF_WSTW  (OFF_SWW + 6144)          // [64][128] bf16 (K=32 real + 0) = 4096

// chunk-XOR swizzle on the k dimension (8-bf16 chunks within 64-k tiles)
#define SWZK(k, x) (((k) & ~63) | (((((k) >> 3) & 7) ^ ((x) & 7)) << 3) | ((k) & 7))
// gbuf row swizzle (8 chunks/row)
#define GSWZ(n) ((((n) >> 3) ^ (n)) & 7)

typedef __attribute__((ext_vector_type(8))) short short8;
typedef __attribute__((ext_vector_type(4))) float f32x4;
typedef const __attribute__((address_space(1))) uint32_t* gas_t;
typedef __attribute__((address_space(3))) uint32_t* las_t;

__device__ __forceinline__ float fast_rcp(float x) { return __builtin_amdgcn_rcpf(x); }
__device__ __forceinline__ float fast_tanh(float x) {
    x = fminf(fmaxf(x, -10.f), 10.f);
    float e = __expf(2.f * x);
    return (e - 1.f) * fast_rcp(e + 1.f);
}
__device__ __forceinline__ float fast_sigmoid(float x) {
    return fast_rcp(1.f + __expf(-x));
}
// RNE f32->bf16 (proven bit-path; v_cvt_pk_bf16_f32 regressed absmax 13x in r8)
__device__ __forceinline__ unsigned short f2bf(float f) {
    uint32_t u = __float_as_uint(f);
    u += 0x7fff + ((u >> 16) & 1);
    return (unsigned short)(u >> 16);
}
__device__ __forceinline__ float bf2f(unsigned short b) {
    return __uint_as_float(((uint32_t)b) << 16);
}

// ---------------- K0: precompute (parallelized over 64 blocks; r10 layouts) ----------------
__global__ __launch_bounds__(256) void prep_kernel(const float* __restrict__ gcn_w,
                            const float* __restrict__ h0_w1, const float* __restrict__ h0_b1,
                            const float* __restrict__ h1_w1, const float* __restrict__ h1_b1,
                            const float* __restrict__ task_emb,
                            const float* __restrict__ filt_w, const float* __restrict__ gate_w,
                            const float* __restrict__ skip_w, const float* __restrict__ start_w,
                            float* __restrict__ c01, float* __restrict__ wgcnT,
                            float* __restrict__ w1tT,
                            unsigned short* __restrict__ waw,
                            unsigned short* __restrict__ sww,
                            unsigned short* __restrict__ wstw)
{
    const int GS = 64 * 256;
    int gt = blockIdx.x * 256 + threadIdx.x;
    for (int idx = gt; idx < 64 * 192; idx += GS) {
        int o = idx / 192, j = idx % 192;
        wgcnT[j * 64 + o] = gcn_w[idx];
    }
    for (int idx = gt; idx < 4096; idx += GS) {
        int o = idx >> 6, c = idx & 63;
        w1tT[c * 64 + o]        = h0_w1[o * 128 + 64 + c];
        w1tT[4096 + c * 64 + o] = h1_w1[o * 128 + 64 + c];
    }
    // WA[L][r][k]: r<64 filt, r>=64 gate; k = tap*64 + c; 16 chunks swizzled ^(r&15)
    for (int job = gt; job < 3 * 128 * 16; job += GS) {
        int L = job / 2048, rem = job % 2048;
        int r = rem >> 4, chp = rem & 15;
        int cho = chp ^ (r & 15);
        #pragma unroll
        for (int i = 0; i < 8; ++i) {
            int k = cho * 8 + i, tap = k >> 6, c = k & 63;
            float v = (r < 64) ? filt_w[L * 8192 + r * 128 + c * 2 + tap]
                               : gate_w[L * 8192 + (r - 64) * 128 + c * 2 + tap];
            waw[((L * 128 + r) * 16 + chp) * 8 + i] = f2bf(v);
        }
    }
    // SW[L][r][c] 8 chunks swizzled ^(r&7), all 3 layers
    for (int job = gt; job < 3 * 64 * 8; job += GS) {
        int L = job / 512, rem = job % 512;
        int r = rem >> 3, chp = rem & 7;
        int cho = chp ^ (r & 7);
        #pragma unroll
        for (int i = 0; i < 8; ++i)
            sww[((L * 64 + r) * 8 + chp) * 8 + i] = f2bf(skip_w[L * 4096 + r * 64 + cho * 8 + i]);
    }
    // Wstart[r][k] K=128 layout (k<16 real, else 0), 16 chunks swizzled ^(r&15)
    for (int job = gt; job < 64 * 16; job += GS) {
        int r = job >> 4, chp = job & 15;
        int cho = chp ^ (r & 15);
        #pragma unroll
        for (int i = 0; i < 8; ++i) {
            int k = cho * 8 + i;
            wstw[(r * 16 + chp) * 8 + i] = (k < 16) ? f2bf(start_w[r * 16 + k]) : (unsigned short)0;
        }
    }
    if (gt < 128) {
        int head = gt >> 6, o = gt & 63;
        const float* w1 = head ? h1_w1 : h0_w1;
        const float* b1 = head ? h1_b1 : h0_b1;
        float a = b1[o];
        for (int k = 0; k < 64; ++k) a = fmaf(w1[o * 128 + k], task_emb[k], a);
        c01[gt] = a;
    }
}

// ---------------- K1: adpF = softmax(relu(nv1@nv2), axis=1), fp32, coalesced ----------------
__global__ __launch_bounds__(256) void adp_kernel(const float* __restrict__ nv1,
                                                  const float* __restrict__ nv2,
                                                  float* __restrict__ adpF)
{
    __shared__ float nv1s[10];
    __shared__ float rbuf[4];
    int tid = threadIdx.x;
    int r = blockIdx.x;
    if (tid < 10) nv1s[tid] = nv1[r * 10 + tid];
    __syncthreads();

    float val[8];
    float vmax = -3.4e38f;
    #pragma unroll
    for (int s = 0; s < 8; ++s) {
        int j = tid + s * 256;
        if (j < NN) {
            float v = 0.f;
            #pragma unroll
            for (int k = 0; k < 10; ++k) v = fmaf(nv1s[k], nv2[k * NN + j], v);
            v = fmaxf(v, 0.f);
            val[s] = v;
            vmax = fmaxf(vmax, v);
        } else val[s] = -3.4e38f;
    }
    for (int off = 32; off; off >>= 1) vmax = fmaxf(vmax, __shfl_down(vmax, off, 64));
    if ((tid & 63) == 0) rbuf[tid >> 6] = vmax;
    __syncthreads();
    vmax = fmaxf(fmaxf(rbuf[0], rbuf[1]), fmaxf(rbuf[2], rbuf[3]));
    __syncthreads();
    float sum = 0.f;
    #pragma unroll
    for (int s = 0; s < 8; ++s) {
        int j = tid + s * 256;
        if (j < NN) { val[s] = expf(val[s] - vmax); sum += val[s]; }
    }
    for (int off = 32; off; off >>= 1) sum += __shfl_down(sum, off, 64);
    if ((tid & 63) == 0) rbuf[tid >> 6] = sum;
    __syncthreads();
    sum = rbuf[0] + rbuf[1] + rbuf[2] + rbuf[3];
    float inv = 1.f / sum;
    #pragma unroll
    for (int s = 0; s < 8; ++s) {
        int j = tid + s * 256;
        if (j < NN) adpF[(size_t)r * NPAD + j] = val[s] * inv;
    }
}

// ---------------- K1b: adpT = transpose(adpF) -> bf16, k-swizzled, zero-padded ----------------
__global__ __launch_bounds__(256) void transpose_adp(const float* __restrict__ adpF,
                                                     unsigned short* __restrict__ adpT)
{
    __shared__ float tile[64][65];
    int tid = threadIdx.x;
    int r0 = blockIdx.x * 64;
    int j0 = blockIdx.y * 64;
    #pragma unroll
    for (int s = 0; s < 16; ++s) {
        int idx = s * 256 + tid;
        int i = idx >> 6, jj = idx & 63;
        int r = r0 + i, j = j0 + jj;
        tile[i][jj] = (r < NN && j < NN) ? adpF[(size_t)r * NPAD + j] : 0.f;
    }
    __syncthreads();
    #pragma unroll
    for (int s = 0; s < 2; ++s) {
        int slot = s * 256 + tid;
        int j = slot >> 3, ch = slot & 7;
        short8 v;
        #pragma unroll
        for (int e = 0; e < 8; ++e) v[e] = (short)f2bf(tile[ch * 8 + e][j]);
        *(short8*)&adpT[(size_t)(j0 + j) * NPAD + r0 + ((ch ^ (j & 7)) << 3)] = v;
    }
}

// ---------------- K2: fused temporal stack (r10-exact: dup-tap, SW all-resident) ----------------
template<int NG, int WOUT>
__device__ __forceinline__ void mfma_phaseB(int L,
    const unsigned short* __restrict__ xb, unsigned short* __restrict__ gbuf,
    const unsigned short* __restrict__ WA, const float* __restrict__ biasAll,
    int wave, int lr, int lk)
{
    if (wave >= NG) return;
    int idx = wave * 16 + lr;
    int n = (idx / WOUT) * 8 + (idx % WOUT);
    f32x4 aF[4], aG[4];
    #pragma unroll
    for (int mt = 0; mt < 4; ++mt) {
        aF[mt] = (f32x4){0.f, 0.f, 0.f, 0.f};
        aG[mt] = (f32x4){0.f, 0.f, 0.f, 0.f};
    }
    #pragma unroll
    for (int ks = 0; ks < 4; ++ks) {
        short8 bv = *(const short8*)&xb[(n * 16 + ((ks * 4 + lk) ^ (n & 15))) * 8];
        #pragma unroll
        for (int mt = 0; mt < 4; ++mt) {
            int r = mt * 16 + lr;
            short8 av = *(const short8*)&WA[(r * 16 + ((ks * 4 + lk) ^ (r & 15))) * 8];
            aF[mt] = __builtin_amdgcn_mfma_f32_16x16x32_bf16(av, bv, aF[mt], 0, 0, 0);
        }
        #pragma unroll
        for (int mt = 0; mt < 4; ++mt) {
            int r = (mt + 4) * 16 + lr;
            short8 av = *(const short8*)&WA[(r * 16 + ((ks * 4 + lk) ^ (r & 15))) * 8];
            aG[mt] = __builtin_amdgcn_mfma_f32_16x16x32_bf16(av, bv, aG[mt], 0, 0, 0);
        }
    }
    int gs = GSWZ(n);
    #pragma unroll
    for (int mt = 0; mt < 4; ++mt) {
        int ob = mt * 16 + lk * 4;
        ushort4 p;
        p.x = f2bf(fast_tanh(aF[mt][0] + biasAll[L * 128 + ob + 0]) * fast_sigmoid(aG[mt][0] + biasAll[L * 128 + 64 + ob + 0]));
        p.y = f2bf(fast_tanh(aF[mt][1] + biasAll[L * 128 + ob + 1]) * fast_sigmoid(aG[mt][1] + biasAll[L * 128 + 64 + ob + 1]));
        p.z = f2bf(fast_tanh(aF[mt][2] + biasAll[L * 128 + ob + 2]) * fast_sigmoid(aG[mt][2] + biasAll[L * 128 + 64 + ob + 2]));
        p.w = f2bf(fast_tanh(aF[mt][3] + biasAll[L * 128 + ob + 3]) * fast_sigmoid(aG[mt][3] + biasAll[L * 128 + 64 + ob + 3]));
        *(ushort4*)&gbuf[((n * 8) + ((mt * 2 + (lk >> 1)) ^ gs)) * 8 + (lk & 1) * 4] = p;
    }
}

template<int L, int D, int WOUT, int DN>
__device__ __forceinline__ void phaseC_conv(unsigned short* __restrict__ xb,
    const unsigned short* __restrict__ gbuf,
    const float* __restrict__ bn_g, const float* __restrict__ bn_b,
    float xreg[2][8], int wave, int o)
{
    const int WOUT_NEXT = WOUT - DN;
    float bsc = bn_g[L * 64 + o] * rsqrtf(1.0f + 1e-5f);
    float bsh = bn_b[L * 64 + o];
    #pragma unroll
    for (int gi = 0; gi < 2; ++gi) {
        int g = wave * 2 + gi;
        #pragma unroll
        for (int t = 0; t < WOUT; ++t) {
            int n = g * 8 + t;
            float gv = bf2f(gbuf[(n * 8 + ((o >> 3) ^ GSWZ(n))) * 8 + (o & 7)]);
            float nx = (gv + xreg[gi][t + D]) * bsc + bsh;
            xreg[gi][t] = nx;
            unsigned short bfv = f2bf(nx);
            if (t < WOUT_NEXT)
                xb[(n * 16 + ((o >> 3) ^ (n & 15))) * 8 + (o & 7)] = bfv;
            if (t >= DN) {
                int n1 = n - DN;
                xb[(n1 * 16 + (((o >> 3) + 8) ^ (n1 & 15))) * 8 + (o & 7)] = bfv;
            }
        }
    }
}

__device__ __forceinline__ void phaseC_skip(int L, int LASTT,
    const unsigned short* __restrict__ gbuf, const unsigned short* __restrict__ SW,
    f32x4 skacc[4], int wave, int lr, int lk)
{
    if (wave >= 2) return;
    int g = wave * 16 + lr;
    int n = g * 8 + LASTT;
    int gs = GSWZ(n);
    #pragma unroll
    for (int ks = 0; ks < 2; ++ks) {
        short8 bv = *(const short8*)&gbuf[(n * 8 + ((ks * 4 + lk) ^ gs)) * 8];
        #pragma unroll
        for (int mt = 0; mt < 4; ++mt) {
            int r = mt * 16 + lr;
            short8 av = *(const short8*)&SW[((L * 64 + r) * 8 + ((ks * 4 + lk) ^ (r & 7))) * 8];
            skacc[mt] = __builtin_amdgcn_mfma_f32_16x16x32_bf16(av, bv, skacc[mt], 0, 0, 0);
        }
    }
}

__global__ __launch_bounds__(1024) void temporal_kernel(
    const float* __restrict__ X,
    const float* __restrict__ start_b,
    const unsigned short* __restrict__ waw,
    const unsigned short* __restrict__ sww,
    const unsigned short* __restrict__ wstw,
    const float* __restrict__ filt_b, const float* __restrict__ gate_b,
    const float* __restrict__ skip_b,
    const float* __restrict__ bn_g, const float* __restrict__ bn_b,
    float* __restrict__ S, unsigned short* __restrict__ St)
{
    extern __shared__ float smem[];
    unsigned short* xb   = (unsigned short*)smem;              // 32768 ush [256][128]
    unsigned short* gbuf = (unsigned short*)(smem + 16384);    // 16384 ush
    unsigned short* WA   = (unsigned short*)(smem + 24576);    // 16384 ush
    unsigned short* SW   = (unsigned short*)(smem + 32768);    // 12288 ush (all 3 layers)
    float* biasAll       = smem + 38912;                       // 384 f32

    int tid = threadIdx.x;
    int wave = tid >> 6, lane = tid & 63;
    int lr = lane & 15, lk = lane >> 4;
    int o = lane;
    int item0 = blockIdx.x * 32;

    // ---- init staging ----
    __builtin_amdgcn_global_load_lds((gas_t)(wstw + tid * 8), (las_t)(WA + tid * 8), 16, 0, 0);
    for (int idx = tid; idx < 1536; idx += 1024)
        __builtin_amdgcn_global_load_lds((gas_t)(sww + idx * 8), (las_t)(SW + idx * 8), 16, 0, 0);
    if (tid < 384) {
        int L = tid >> 7, oo = tid & 127;
        biasAll[tid] = (oo < 64) ? filt_b[L * 64 + oo] : gate_b[L * 64 + oo - 64];
    }
    {   // X -> xb
        int n = tid >> 2, c = tid & 3;
        int g = n >> 3, t = n & 7;
        int ig = item0 + g, b = ig / NN, nn = ig - b * NN;
        short8 v = {0, 0, 0, 0, 0, 0, 0, 0};
        if (c < 2) {
            const float* src = &X[((size_t)(b * TT + t) * NN + nn) * NF + c * 8];
            float4 f0 = *(const float4*)src;
            float4 f1 = *(const float4*)(src + 4);
            v[0] = (short)f2bf(f0.x); v[1] = (short)f2bf(f0.y);
            v[2] = (short)f2bf(f0.z); v[3] = (short)f2bf(f0.w);
            v[4] = (short)f2bf(f1.x); v[5] = (short)f2bf(f1.y);
            v[6] = (short)f2bf(f1.z); v[7] = (short)f2bf(f1.w);
        }
        *(short8*)&xb[(n * 16 + (c ^ (n & 15))) * 8] = v;
    }
    __syncthreads();

    // ---- start conv MFMA (K=32, M=64); all 8 t needed as layer-0 taps ----
    {
        f32x4 aS[4];
        #pragma unroll
        for (int mt = 0; mt < 4; ++mt) aS[mt] = (f32x4){0.f, 0.f, 0.f, 0.f};
        int n = wave * 16 + lr;
        short8 bv = *(const short8*)&xb[(n * 16 + (lk ^ (n & 15))) * 8];
        #pragma unroll
        for (int mt = 0; mt < 4; ++mt) {
            int r = mt * 16 + lr;
            short8 av = *(const short8*)&WA[(r * 16 + (lk ^ (r & 15))) * 8];
            aS[mt] = __builtin_amdgcn_mfma_f32_16x16x32_bf16(av, bv, aS[mt], 0, 0, 0);
        }
        int gs = GSWZ(n);
        #pragma unroll
        for (int mt = 0; mt < 4; ++mt) {
            ushort4 p;
            p.x = f2bf(aS[mt][0]); p.y = f2bf(aS[mt][1]);
            p.z = f2bf(aS[mt][2]); p.w = f2bf(aS[mt][3]);
            *(ushort4*)&gbuf[((n * 8) + ((mt * 2 + (lk >> 1)) ^ gs)) * 8 + (lk & 1) * 4] = p;
        }
    }
    __syncthreads();

    float xreg[2][8];
    f32x4 skacc[4];
    #pragma unroll
    for (int mt = 0; mt < 4; ++mt) skacc[mt] = (f32x4){0.f, 0.f, 0.f, 0.f};

    // ---- C0: x = start_out + start_b; taps for layer0 (D=1); stage WA L0 ----
    {
        __builtin_amdgcn_global_load_lds((gas_t)(waw + (size_t)tid * 8),
                                         (las_t)(WA + tid * 8), 16, 0, 0);
        __builtin_amdgcn_global_load_lds((gas_t)(waw + (size_t)(tid + 1024) * 8),
                                         (las_t)(WA + (tid + 1024) * 8), 16, 0, 0);
        float sb = start_b[o];
        #pragma unroll
        for (int gi = 0; gi < 2; ++gi) {
            int g = wave * 2 + gi;
            #pragma unroll
            for (int t = 0; t < 8; ++t) {
                int n = g * 8 + t;
                float gv = bf2f(gbuf[(n * 8 + ((o >> 3) ^ GSWZ(n))) * 8 + (o & 7)]) + sb;
                xreg[gi][t] = gv;
                unsigned short bfv = f2bf(gv);
                if (t < 7)
                    xb[(n * 16 + ((o >> 3) ^ (n & 15))) * 8 + (o & 7)] = bfv;
                if (t >= 1) {
                    int n1 = n - 1;
                    xb[(n1 * 16 + (((o >> 3) + 8) ^ (n1 & 15))) * 8 + (o & 7)] = bfv;
                }
            }
        }
    }
    __syncthreads();

    // ---- layer 0 (live t<7: 224 rows = 14 groups) ----
    mfma_phaseB<14, 7>(0, xb, gbuf, WA, biasAll, wave, lr, lk);
    __syncthreads();
    phaseC_skip(0, 6, gbuf, SW, skacc, wave, lr, lk);
    phaseC_conv<0, 1, 7, 2>(xb, gbuf, bn_g, bn_b, xreg, wave, o);
    __builtin_amdgcn_global_load_lds((gas_t)(waw + (size_t)(2048 + tid) * 8),
                                     (las_t)(WA + tid * 8), 16, 0, 0);
    __builtin_amdgcn_global_load_lds((gas_t)(waw + (size_t)(2048 + tid + 1024) * 8),
                                     (las_t)(WA + (tid + 1024) * 8), 16, 0, 0);
    __syncthreads();

    // ---- layer 1 (live t<5: 160 rows = 10 groups) ----
    mfma_phaseB<10, 5>(1, xb, gbuf, WA, biasAll, wave, lr, lk);
    __syncthreads();
    phaseC_skip(1, 4, gbuf, SW, skacc, wave, lr, lk);
    phaseC_conv<1, 2, 5, 4>(xb, gbuf, bn_g, bn_b, xreg, wave, o);
    __builtin_amdgcn_global_load_lds((gas_t)(waw + (size_t)(4096 + tid) * 8),
                                     (las_t)(WA + tid * 8), 16, 0, 0);
    __builtin_amdgcn_global_load_lds((gas_t)(waw + (size_t)(4096 + tid + 1024) * 8),
                                     (las_t)(WA + (tid + 1024) * 8), 16, 0, 0);
    __syncthreads();

    // ---- layer 2 (live t<1: 32 rows = 2 groups) ----
    mfma_phaseB<2, 1>(2, xb, gbuf, WA, biasAll, wave, lr, lk);
    __syncthreads();
    phaseC_skip(2, 0, gbuf, SW, skacc, wave, lr, lk);

    // ---- final skip writes ----
    if (wave < 2) {
        int g = wave * 16 + lr;
        int ig = item0 + g, b = ig / NN, nn = ig - b * NN;
        #pragma unroll
        for (int mt = 0; mt < 4; ++mt) {
            #pragma unroll
            for (int j = 0; j < 4; ++j) {
                int oo = mt * 16 + lk * 4 + j;
                float v = skacc[mt][j] + skip_b[oo] + skip_b[64 + oo] + skip_b[128 + oo];
                int bc = b * 64 + oo;
                S[(size_t)nn * BCD + bc] = v;
                St[(size_t)bc * NPAD + SWZK(nn, oo)] = f2bf(v);
            }
        }
    }
}

// ---------------- K3: bf16 MFMA GEMM, C[m][n] = sum_k A[m][k]*B[n][k] ----------------
// 1-D grid of 512 blocks; XCD-aware bijective swizzle (T1): lid' = (lid%8)*64 + lid/8.
__global__ __launch_bounds__(256) void gemm_mfma(
    const unsigned short* __restrict__ A, const unsigned short* __restrict__ B,
    float* __restrict__ Cf, unsigned short* __restrict__ Ct)
{
    __shared__ unsigned short As[128 * 64];
    __shared__ unsigned short Bs[128 * 64];
    int tid = threadIdx.x;
    int wave = tid >> 6, lane = tid & 63;
    int lk = lane >> 4, lr = lane & 15;
    int lid = blockIdx.x;
    int lid2 = (lid & 7) * 64 + (lid >> 3);   // 512 blocks, %8==0 -> bijective
    int bx = lid2 & 31, by = lid2 >> 5;
    int n0 = bx * 128, m0 = by * 128;
    int wm = wave >> 1, wn = wave & 1;

    f32x4 acc[4][4];
    #pragma unroll
    for (int i = 0; i < 4; ++i)
        #pragma unroll
        for (int j = 0; j < 4; ++j)
            acc[i][j] = (f32x4){0.f, 0.f, 0.f, 0.f};

    for (int k0 = 0; k0 < NPAD; k0 += 64) {
        #pragma unroll
        for (int i = 0; i < 4; ++i) {
            int chunk = wave * 4 + i;
            int row = chunk * 8 + (lane >> 3);
            int koff = (lane & 7) * 8;
            __builtin_amdgcn_global_load_lds(
                (gas_t)(A + (size_t)(m0 + row) * NPAD + k0 + koff),
                (las_t)(&As[chunk * 512]), 16, 0, 0);
            __builtin_amdgcn_global_load_lds(
                (gas_t)(B + (size_t)(n0 + row) * NPAD + k0 + koff),
                (las_t)(&Bs[chunk * 512]), 16, 0, 0);
        }
        __syncthreads();
        #pragma unroll
        for (int s = 0; s < 2; ++s) {
            short8 av[4], bv[4];
            #pragma unroll
            for (int f = 0; f < 4; ++f) {
                int m = wm * 64 + f * 16 + lr;
                int ca = ((s * 4 + lk) ^ (m & 7));
                av[f] = *(const short8*)&As[m * 64 + ca * 8];
                int n = wn * 64 + f * 16 + lr;
                int cb = ((s * 4 + lk) ^ (n & 7));
                bv[f] = *(const short8*)&Bs[n * 64 + cb * 8];
            }
            #pragma unroll
            for (int fi = 0; fi < 4; ++fi)
                #pragma unroll
                for (int fj = 0; fj < 4; ++fj)
                    acc[fi][fj] = __builtin_amdgcn_mfma_f32_16x16x32_bf16(
                        av[fi], bv[fj], acc[fi][fj], 0, 0, 0);
        }
        __syncthreads();
    }

    #pragma unroll
    for (int fi = 0; fi < 4; ++fi) {
        #pragma unroll
        for (int fj = 0; fj < 4; ++fj) {
            int m = m0 + wm * 64 + fi * 16 + lk * 4;
            int n = n0 + wn * 64 + fj * 16 + lr;
            f32x4 v = acc[fi][fj];
            if (Cf) {
                Cf[(size_t)(m + 0) * BCD + n] = v[0];
                Cf[(size_t)(m + 1) * BCD + n] = v[1];
                Cf[(size_t)(m + 2) * BCD + n] = v[2];
                Cf[(size_t)(m + 3) * BCD + n] = v[3];
            }
            if (Ct) {
                ushort4 p;
                p.x = f2bf(v[0]); p.y = f2bf(v[1]);
                p.z = f2bf(v[2]); p.w = f2bf(v[3]);
                *(ushort4*)&Ct[(size_t)n * NPAD + SWZK(m, n)] = p;
            }
        }
    }
}

// ---------------- K4: gcn 1x1 + heads + outputs + partial reductions ----------------
__global__ __launch_bounds__(256) void head_kernel(
    const float* __restrict__ S, const float* __restrict__ x1f,
    const float* __restrict__ x2,
    const float* __restrict__ wgcnT, const float* __restrict__ gcn_b,
    const float* __restrict__ c01, const float* __restrict__ w1tT,
    const float* __restrict__ h0_w2, const float* __restrict__ h0_b2,
    const float* __restrict__ h1_w2, const float* __restrict__ h1_b2,
    const int* __restrict__ Ct, const float* __restrict__ Yf,
    float* __restrict__ out, float* __restrict__ partials)
{
    __shared__ float hl[4][4][192];
    __shared__ float gxl[4][4][64];
    int tid = threadIdx.x;
    int wave = tid >> 6, o = tid & 63;
    int wid = blockIdx.x * 4 + wave;
    float w2a = h0_w2[o], w2b = h1_w2[o];
    float b20 = h0_b2[0], b21 = h1_b2[0];
    float cb = gcn_b[o], c0a = c01[o], c0b = c01[64 + o];

    float accT = 0.f, accC = 0.f, bce = 0.f, cT = 0.f, cC = 0.f;

    for (int base = wid * 4; base < ITEMS; base += 2048 * 4) {
        #pragma unroll
        for (int it = 0; it < 4; ++it) {
            int item = base + it;
            int b = item / NN, n = item - b * NN;
            int bc = b * 64 + o;
            hl[wave][it][o]       = S[(size_t)n * BCD + bc];
            hl[wave][it][64 + o]  = x1f[(size_t)n * BCD + bc];
            hl[wave][it][128 + o] = x2[(size_t)n * BCD + bc];
        }
        float a0 = cb, a1 = cb, a2 = cb, a3 = cb;
        for (int j = 0; j < 192; ++j) {
            float w = wgcnT[j * 64 + o];
            a0 = fmaf(w, hl[wave][0][j], a0);
            a1 = fmaf(w, hl[wave][1][j], a1);
            a2 = fmaf(w, hl[wave][2][j], a2);
            a3 = fmaf(w, hl[wave][3][j], a3);
        }
        float gxv[4] = {fmaxf(a0, 0.f), fmaxf(a1, 0.f), fmaxf(a2, 0.f), fmaxf(a3, 0.f)};
        #pragma unroll
        for (int it = 0; it < 4; ++it) gxl[wave][it][o] = gxv[it];

        float p0[4], p1[4];
        #pragma unroll
        for (int it = 0; it < 4; ++it) { p0[it] = c0a; p1[it] = c0b; }
        for (int c = 0; c < 64; ++c) {
            float w0 = w1tT[c * 64 + o];
            float w1 = w1tT[4096 + c * 64 + o];
            float g0 = gxl[wave][0][c], g1 = gxl[wave][1][c];
            float g2 = gxl[wave][2][c], g3 = gxl[wave][3][c];
            p0[0] = fmaf(w0, g0, p0[0]); p0[1] = fmaf(w0, g1, p0[1]);
            p0[2] = fmaf(w0, g2, p0[2]); p0[3] = fmaf(w0, g3, p0[3]);
            p1[0] = fmaf(w1, g0, p1[0]); p1[1] = fmaf(w1, g1, p1[1]);
            p1[2] = fmaf(w1, g2, p1[2]); p1[3] = fmaf(w1, g3, p1[3]);
        }
        #pragma unroll
        for (int it = 0; it < 4; ++it) {
            float r0 = w2a * fmaxf(p0[it], 0.f);
            float r1 = w2b * fmaxf(p1[it], 0.f);
            #pragma unroll
            for (int off = 32; off; off >>= 1) {
                r0 += __shfl_down(r0, off, 64);
                r1 += __shfl_down(r1, off, 64);
            }
            int item = base + it;
            int tt = Ct[item];
            if (o == 0) {
                float y0 = 1.f / (1.f + expf(-(r0 + b20)));
                float y1 = 1.f / (1.f + expf(-(r1 + b21)));
                float y = (tt > 0) ? y1 : y0;
                out[1 + item] = y;
                out[1 + ITEMS + item] = y0;
                out[1 + 2 * ITEMS + item] = y1;
                float yc = fminf(fmaxf(y, 1e-7f), 1.f - 1e-7f);
                float Yv = Yf[item];
                bce -= Yv * logf(yc) + (1.f - Yv) * logf(1.f - yc);
                if (tt > 0) cT += 1.f; else cC += 1.f;
            }
            if (tt > 0) accT += gxv[it]; else accC += gxv[it];
        }
    }
    partials[wid * 132 + o] = accT;
    partials[wid * 132 + 64 + o] = accC;
    if (o == 0) {
        partials[wid * 132 + 128] = bce;
        partials[wid * 132 + 129] = cT;
        partials[wid * 132 + 130] = cC;
    }
}

// ---------------- K5a: parallel slot reduce ----------------
__global__ __launch_bounds__(256) void reduce_kernel(const float* __restrict__ partials,
                                                     float* __restrict__ red)
{
    __shared__ float rb[4];
    int slot = blockIdx.x;
    int tid = threadIdx.x;
    float s = 0.f;
    for (int w = tid; w < 2048; w += 256) s += partials[w * 132 + slot];
    #pragma unroll
    for (int off = 32; off; off >>= 1) s += __shfl_down(s, off, 64);
    if ((tid & 63) == 0) rb[tid >> 6] = s;
    __syncthreads();
    if (tid == 0) red[slot] = rb[0] + rb[1] + rb[2] + rb[3];
}

// ---------------- K5b: final loss ----------------
__global__ void final_kernel(const float* __restrict__ red,
                             const float* __restrict__ task_emb,
                             float* __restrict__ out)
{
    int tid = threadIdx.x; // 64
    float cT = red[129], cC = red[130];
    float iT = 1.f / fmaxf(cT, 1.f), iC = 1.f / fmaxf(cC, 1.f);
    float d1 = task_emb[tid] * (cT * iT) - task_emb[tid] * (cC * iC);
    float d2 = red[tid] * iT - red[64 + tid] * iC;
    float p = d1 * d1 + d2 * d2;
    #pragma unroll
    for (int off = 32; off; off >>= 1) p += __shfl_down(p, off, 64);
    if (tid == 0) out[0] = red[128] * (1.f / (float)ITEMS) + p;
}

// ---------------- launch ----------------
extern "C" void kernel_launch(void* const* d_in, const int* in_sizes, int n_in,
                              void* d_out, int out_size, void* d_ws, size_t ws_size,
                              hipStream_t stream)
{
    const float* X       = (const float*)d_in[0];
    const int*   Ct      = (const int*)d_in[2];
    const float* Yf      = (const float*)d_in[3];
    const float* start_w = (const float*)d_in[5];
    const float* start_b = (const float*)d_in[6];
    const float* filt_w  = (const float*)d_in[7];
    const float* filt_b  = (const float*)d_in[8];
    const float* gate_w  = (const float*)d_in[9];
    const float* gate_b  = (const float*)d_in[10];
    const float* skip_w  = (const float*)d_in[11];
    const float* skip_b  = (const float*)d_in[12];
    const float* bn_g    = (const float*)d_in[13];
    const float* bn_b    = (const float*)d_in[14];
    const float* nv1     = (const float*)d_in[15];
    const float* nv2     = (const float*)d_in[16];
    const float* task    = (const float*)d_in[17];
    const float* gcn_w   = (const float*)d_in[18];
    const float* gcn_b   = (const float*)d_in[19];
    const float* h0_w1   = (const float*)d_in[20];
    const float* h0_b1   = (const float*)d_in[21];
    const float* h0_w2   = (const float*)d_in[22];
    const float* h0_b2   = (const float*)d_in[23];
    const float* h1_w1   = (const float*)d_in[24];
    const float* h1_b1   = (const float*)d_in[25];
    const float* h1_w2   = (const float*)d_in[26];
    const float* h1_b2   = (const float*)d_in[27];

    float* ws    = (float*)d_ws;
    float* adpF  = ws + OFF_ADPF;
    unsigned short* St   = (unsigned short*)(ws + OFF_ST);
    float* x2    = ws + OFF_X2;        // aliases [adpF|St], safe by schedule
    unsigned short* adpT = (unsigned short*)(ws + OFF_ADPT);
    float* S     = ws + OFF_S;
    float* x1f   = ws + OFF_X1F;
    unsigned short* x1t  = (unsigned short*)(ws + OFF_X1T);
    float* c01   = ws + OFF_C01;
    float* wgcnT = ws + OFF_WGCNT;
    float* w1tT  = ws + OFF_W1TT;
    float* part  = ws + OFF_PART;
    float* red   = ws + OFF_RED;
    unsigned short* waw  = (unsigned short*)(ws + OFF_WAW);
    unsigned short* sww  = (unsigned short*)(ws + OFF_SWW);
    unsigned short* wstw = (unsigned short*)(ws + OFF_WSTW);
    float* outp  = (float*)d_out;

    // zero St (pad columns n in [2000,2048) must contribute 0 to GEMM1)
    hipMemsetAsync(St, 0, (size_t)BCD * NPAD * sizeof(unsigned short), stream);

    prep_kernel<<<64, 256, 0, stream>>>(gcn_w, h0_w1, h0_b1, h1_w1, h1_b1, task,
                                        filt_w, gate_w, skip_w, start_w,
                                        c01, wgcnT, w1tT, waw, sww, wstw);
    adp_kernel<<<NN, 256, 0, stream>>>(nv1, nv2, adpF);
    dim3 tg(NPAD / 64, NPAD / 64);
    transpose_adp<<<tg, 256, 0, stream>>>(adpF, adpT);

    const int K2_LDS = 39296 * 4; // 153.5 KiB dynamic LDS (r10-exact)
    hipFuncSetAttribute(reinterpret_cast<const void*>(temporal_kernel),
                        hipFuncAttributeMaxDynamicSharedMemorySize, K2_LDS);
    temporal_kernel<<<ITEMS / 32, 1024, K2_LDS, stream>>>(
        X, start_b, waw, sww, wstw, filt_b, gate_b,
        skip_b, bn_g, bn_b, S, St);

    gemm_mfma<<<512, 256, 0, stream>>>(adpT, St, x1f, x1t);      // x1 (both layouts)
    gemm_mfma<<<512, 256, 0, stream>>>(adpT, x1t, x2, nullptr);  // x2 = adp^T·x1

    head_kernel<<<512, 256, 0, stream>>>(S, x1f, x2, wgcnT, gcn_b, c01, w1tT,
                                         h0_w2, h0_b2, h1_w2, h1_b2,
                                         Ct, Yf, outp, part);
    reduce_kernel<<<131, 256, 0, stream>>>(part, red);
    final_kernel<<<1, 64, 0, stream>>>(red, task, outp);
}